// Round 6
// baseline (364.575 us; speedup 1.0000x reference)
//
#include <hip/hip_runtime.h>
#include <hip/hip_bf16.h>

#define Bb 4
#define Nn 4096
#define C1 320
#define C2 256
#define Hh 5
#define HD 64
#define Mm (Bb*Nn)   // 16384

using bf16 = __hip_bfloat16;
typedef __attribute__((ext_vector_type(8))) short  short8;   // 8 bf16 = one MFMA A/B frag
typedef __attribute__((ext_vector_type(4))) short  short4_;
typedef __attribute__((ext_vector_type(4))) float  f32x4;    // 16x16 MFMA C/D frag
typedef __attribute__((ext_vector_type(16))) float f32x16;   // 32x32 MFMA C/D frag

__device__ __forceinline__ short f2s(float f) {
    bf16 h = __float2bfloat16(f);
    short s;
    __builtin_memcpy(&s, &h, 2);
    return s;
}

__device__ __forceinline__ float fexp2(float x) {
#if __has_builtin(__builtin_amdgcn_exp2f)
    return __builtin_amdgcn_exp2f(x);
#else
    return exp2f(x);
#endif
}

// XOR-swizzled LDS tile addressing: 64-elem rows, 8 blocks of 8 bf16 (16B).
// physical elem offset of (row, logical block bb) = row*64 + (bb ^ (row&7))*8
__device__ __forceinline__ int swz(int row, int bb) {
    return row * 64 + ((bb ^ (row & 7)) << 3);
}

// pack two f32 -> one dword of 2 bf16 (src0 -> low half)
__device__ __forceinline__ unsigned cvtpk(float lo, float hi) {
    unsigned r;
    asm("v_cvt_pk_bf16_f32 %0, %1, %2" : "=v"(r) : "v"(lo), "v"(hi));
    return r;
}

// swap: a[lanes 32..63] <- b[lanes 0..31]; b[lanes 0..31] <- a[lanes 32..63]
__device__ __forceinline__ void plswap(unsigned &a, unsigned &b) {
#if __has_builtin(__builtin_amdgcn_permlane32_swap)
    auto r = __builtin_amdgcn_permlane32_swap(a, b, false, false);
    a = r[0]; b = r[1];
#else
    asm("v_permlane32_swap_b32 %0, %1" : "+v"(a), "+v"(b));
#endif
}

__device__ __forceinline__ short8 mk8(unsigned d0, unsigned d1, unsigned d2, unsigned d3) {
    union { unsigned u[4]; short8 s; } u;
    u.u[0] = d0; u.u[1] = d1; u.u[2] = d2; u.u[3] = d3;
    return u.s;
}

// ---------------- fp32 -> bf16 convert, all 8 tensors in one launch ----------------
struct CvtArgs {
    const float* s[8];
    bf16* d[8];
    int off[9];   // cumulative offsets, off[8] = total
};

__global__ void cvt_all(CvtArgs a) {
    int i = (blockIdx.x * blockDim.x + threadIdx.x) * 4;
    if (i >= a.off[8]) return;
    int seg = 0;
    #pragma unroll
    for (int k = 1; k < 8; ++k) seg += (i >= a.off[k]);
    int j = i - a.off[seg];
    float4 v = *(const float4*)(a.s[seg] + j);
    short4_ o = { f2s(v.x), f2s(v.y), f2s(v.z), f2s(v.w) };
    *(short4_*)(a.d[seg] + j) = o;
}

// ---------------- fused projection GEMM: 128x64 tile, both inputs in one launch --------
// by in [0,30): g = by/15 selects input set (0: x1-set K=320, 1: x2-set K=256), yy = by%15.
// yy < 5 : Q-part:  Qo[row*320+col] = bf16(acc * qs)          (W = Wq,  Nout=320)
// yy >= 5: KV-part: col<320 -> Ko[row*320+col] = bf16(acc)    (W = Wkv, Nout=640)
//                   col>=320 -> Vo transposed [B,H,64,N]
// 4 waves; wave computes 32 m-rows x 64 n-cols (2 m-frags x 4 n-frags).
__global__ __launch_bounds__(256) void gemm_proj(
    const bf16* __restrict__ A1, const bf16* __restrict__ Wq1, const bf16* __restrict__ Wkv1,
    const bf16* __restrict__ A2, const bf16* __restrict__ Wq2, const bf16* __restrict__ Wkv2,
    float qs,
    bf16* __restrict__ Qo1, bf16* __restrict__ Ko1, bf16* __restrict__ Vo1,
    bf16* __restrict__ Qo2, bf16* __restrict__ Ko2, bf16* __restrict__ Vo2)
{
    __shared__ bf16 la[128 * 64];
    __shared__ bf16 lw[64 * 64];
    const int m0 = blockIdx.x * 128;
    const int by = blockIdx.y;
    const int g = (by >= 15);
    const int yy = by - 15 * g;
    const int K = g ? C2 : C1;
    const bf16* A = g ? A2 : A1;
    const bool isq = yy < 5;
    const bf16* W = isq ? (g ? Wq2 : Wq1) : (g ? Wkv2 : Wkv1);
    bf16* Qo = g ? Qo2 : Qo1;
    bf16* Ko = g ? Ko2 : Ko1;
    bf16* Vo = g ? Vo2 : Vo1;
    const int n0 = (isq ? yy : yy - 5) * 64;
    const int t = threadIdx.x;
    const int wave = t >> 6, lane = t & 63, l16 = lane & 15, quad = lane >> 4;
    const int sr = t >> 3, sb = t & 7;      // sr 0..31, sb 0..7

    f32x4 acc[2][4];
    #pragma unroll
    for (int mf = 0; mf < 2; ++mf)
        #pragma unroll
        for (int nt = 0; nt < 4; ++nt) acc[mf][nt] = {0.f,0.f,0.f,0.f};

    const int nk = K >> 6;
    const bf16* ap = A + (size_t)(m0 + sr) * K + sb * 8;
    const bf16* wp = W + (size_t)(n0 + sr) * K + sb * 8;
    short8 ra0 = *(const short8*)ap;
    short8 ra1 = *(const short8*)(ap + (size_t)32 * K);
    short8 ra2 = *(const short8*)(ap + (size_t)64 * K);
    short8 ra3 = *(const short8*)(ap + (size_t)96 * K);
    short8 rw0 = *(const short8*)wp;
    short8 rw1 = *(const short8*)(wp + (size_t)32 * K);

    for (int kt = 0; kt < nk; ++kt) {
        __syncthreads();
        *(short8*)&la[swz(sr,      sb)] = ra0;
        *(short8*)&la[swz(sr + 32, sb)] = ra1;
        *(short8*)&la[swz(sr + 64, sb)] = ra2;
        *(short8*)&la[swz(sr + 96, sb)] = ra3;
        *(short8*)&lw[swz(sr,      sb)] = rw0;
        *(short8*)&lw[swz(sr + 32, sb)] = rw1;
        __syncthreads();
        if (kt + 1 < nk) {
            ap += 64; wp += 64;
            ra0 = *(const short8*)ap;
            ra1 = *(const short8*)(ap + (size_t)32 * K);
            ra2 = *(const short8*)(ap + (size_t)64 * K);
            ra3 = *(const short8*)(ap + (size_t)96 * K);
            rw0 = *(const short8*)wp;
            rw1 = *(const short8*)(wp + (size_t)32 * K);
        }
        const int arow = wave * 32 + l16;
        short8 a00 = *(const short8*)&la[swz(arow,      quad)];
        short8 a01 = *(const short8*)&la[swz(arow,      quad + 4)];
        short8 a10 = *(const short8*)&la[swz(arow + 16, quad)];
        short8 a11 = *(const short8*)&la[swz(arow + 16, quad + 4)];
        #pragma unroll
        for (int nt = 0; nt < 4; ++nt) {
            const int brow = nt * 16 + l16;
            short8 b0 = *(const short8*)&lw[swz(brow, quad)];
            short8 b1 = *(const short8*)&lw[swz(brow, quad + 4)];
            acc[0][nt] = __builtin_amdgcn_mfma_f32_16x16x32_bf16(a00, b0, acc[0][nt], 0, 0, 0);
            acc[0][nt] = __builtin_amdgcn_mfma_f32_16x16x32_bf16(a01, b1, acc[0][nt], 0, 0, 0);
            acc[1][nt] = __builtin_amdgcn_mfma_f32_16x16x32_bf16(a10, b0, acc[1][nt], 0, 0, 0);
            acc[1][nt] = __builtin_amdgcn_mfma_f32_16x16x32_bf16(a11, b1, acc[1][nt], 0, 0, 0);
        }
    }

    const bool isv = !isq && n0 >= C1;     // whole block is V-part or not
    #pragma unroll
    for (int mf = 0; mf < 2; ++mf) {
        const int mrow = m0 + wave * 32 + mf * 16 + quad * 4;
        if (isq) {
            #pragma unroll
            for (int nt = 0; nt < 4; ++nt) {
                int col = n0 + nt * 16 + l16;
                #pragma unroll
                for (int r = 0; r < 4; ++r)
                    Qo[(size_t)(mrow + r) * C1 + col] = __float2bfloat16(acc[mf][nt][r] * qs);
            }
        } else if (!isv) {
            #pragma unroll
            for (int nt = 0; nt < 4; ++nt) {
                int col = n0 + nt * 16 + l16;
                #pragma unroll
                for (int r = 0; r < 4; ++r)
                    Ko[(size_t)(mrow + r) * C1 + col] = __float2bfloat16(acc[mf][nt][r]);
            }
        } else {
            #pragma unroll
            for (int nt = 0; nt < 4; ++nt) {
                int col = n0 + nt * 16 + l16 - C1;
                int h = col >> 6, d = col & 63;
                #pragma unroll
                for (int r = 0; r < 4; ++r) {
                    int m = mrow + r;
                    int b = m >> 12, n = m & (Nn - 1);
                    Vo[((size_t)(b * Hh + h) * 64 + d) * Nn + n] = __float2bfloat16(acc[mf][nt][r]);
                }
            }
        }
    }
}

// ---------------- fused output projections: 128x64 tile, z = branch ----------------
// Of[row*640 + z*320 + col] = acc + bias[col]
__global__ __launch_bounds__(256) void gemm_out(
    const bf16* __restrict__ Y1, const bf16* __restrict__ Wp1, const float* __restrict__ B1,
    const bf16* __restrict__ Y2, const bf16* __restrict__ Wp2, const float* __restrict__ B2,
    float* __restrict__ Of)
{
    __shared__ bf16 la[128 * 64];
    __shared__ bf16 lw[64 * 64];
    const int zz = blockIdx.z;
    const bf16* A = zz ? Y2 : Y1;
    const bf16* W = zz ? Wp2 : Wp1;
    const float* bias = zz ? B2 : B1;
    const int ooff = zz ? C1 : 0;
    const int m0 = blockIdx.x * 128, n0 = blockIdx.y * 64;
    const int t = threadIdx.x;
    const int wave = t >> 6, lane = t & 63, l16 = lane & 15, quad = lane >> 4;
    const int sr = t >> 3, sb = t & 7;
    const int K = C1;

    f32x4 acc[2][4];
    #pragma unroll
    for (int mf = 0; mf < 2; ++mf)
        #pragma unroll
        for (int nt = 0; nt < 4; ++nt) acc[mf][nt] = {0.f,0.f,0.f,0.f};

    const int nk = K >> 6;
    const bf16* ap = A + (size_t)(m0 + sr) * K + sb * 8;
    const bf16* wp = W + (size_t)(n0 + sr) * K + sb * 8;
    short8 ra0 = *(const short8*)ap;
    short8 ra1 = *(const short8*)(ap + (size_t)32 * K);
    short8 ra2 = *(const short8*)(ap + (size_t)64 * K);
    short8 ra3 = *(const short8*)(ap + (size_t)96 * K);
    short8 rw0 = *(const short8*)wp;
    short8 rw1 = *(const short8*)(wp + (size_t)32 * K);

    for (int kt = 0; kt < nk; ++kt) {
        __syncthreads();
        *(short8*)&la[swz(sr,      sb)] = ra0;
        *(short8*)&la[swz(sr + 32, sb)] = ra1;
        *(short8*)&la[swz(sr + 64, sb)] = ra2;
        *(short8*)&la[swz(sr + 96, sb)] = ra3;
        *(short8*)&lw[swz(sr,      sb)] = rw0;
        *(short8*)&lw[swz(sr + 32, sb)] = rw1;
        __syncthreads();
        if (kt + 1 < nk) {
            ap += 64; wp += 64;
            ra0 = *(const short8*)ap;
            ra1 = *(const short8*)(ap + (size_t)32 * K);
            ra2 = *(const short8*)(ap + (size_t)64 * K);
            ra3 = *(const short8*)(ap + (size_t)96 * K);
            rw0 = *(const short8*)wp;
            rw1 = *(const short8*)(wp + (size_t)32 * K);
        }
        const int arow = wave * 32 + l16;
        short8 a00 = *(const short8*)&la[swz(arow,      quad)];
        short8 a01 = *(const short8*)&la[swz(arow,      quad + 4)];
        short8 a10 = *(const short8*)&la[swz(arow + 16, quad)];
        short8 a11 = *(const short8*)&la[swz(arow + 16, quad + 4)];
        #pragma unroll
        for (int nt = 0; nt < 4; ++nt) {
            const int brow = nt * 16 + l16;
            short8 b0 = *(const short8*)&lw[swz(brow, quad)];
            short8 b1 = *(const short8*)&lw[swz(brow, quad + 4)];
            acc[0][nt] = __builtin_amdgcn_mfma_f32_16x16x32_bf16(a00, b0, acc[0][nt], 0, 0, 0);
            acc[0][nt] = __builtin_amdgcn_mfma_f32_16x16x32_bf16(a01, b1, acc[0][nt], 0, 0, 0);
            acc[1][nt] = __builtin_amdgcn_mfma_f32_16x16x32_bf16(a10, b0, acc[1][nt], 0, 0, 0);
            acc[1][nt] = __builtin_amdgcn_mfma_f32_16x16x32_bf16(a11, b1, acc[1][nt], 0, 0, 0);
        }
    }

    #pragma unroll
    for (int mf = 0; mf < 2; ++mf) {
        const int mrow = m0 + wave * 32 + mf * 16 + quad * 4;
        #pragma unroll
        for (int nt = 0; nt < 4; ++nt) {
            int col = n0 + nt * 16 + l16;
            float bv = bias[col];
            #pragma unroll
            for (int r = 0; r < 4; ++r)
                Of[(size_t)(mrow + r) * 640 + ooff + col] = acc[mf][nt][r] + bv;
        }
    }
}

// ---------------- flash attention, both branches in one launch ----------------
// OCCUPANCY version of the proven R1 structure: each wave owns 32 q-rows (one
// 32x32 q-block) instead of 64, doubling wave count to 5120 (4-5 waves/SIMD)
// so QK-MFMA -> exp -> cvt -> PV-MFMA serial chains hide across waves.
// Per-wave VGPR roughly halves (o: 2x f32x16, qf: 4x short8).
// All else identical to R1: swapped QK^T 32x32 MFMA (lane holds P-row slice:
// q = lane&31, k = (r&3)+8*(r>>2)+4*hi), in-register P->bf16 via
// cvt_pk + permlane32_swap, VALU lsum, fixed m=0 softmax (Q pre-scaled),
// 16KB swizzled LDS K/V tiles, register-prefetched staging, 2 barriers/kt.
// Block = 4 waves x 32 q = 128 q-rows; grid = 32 x 5 x 8 = 1280 blocks.
__global__ __launch_bounds__(256, 4) void flash_kernel(
    const bf16* __restrict__ Q1, const bf16* __restrict__ K1,
    const bf16* __restrict__ V1, bf16* __restrict__ Y1,
    const bf16* __restrict__ Q2, const bf16* __restrict__ K2,
    const bf16* __restrict__ V2, bf16* __restrict__ Y2)
{
    __shared__ bf16 lk[64 * 64];        // K tile [k][d], swizzled
    __shared__ bf16 lv[64 * 64];        // V tile [d][k], swizzled (from pre-transposed Vt)
    const int qt = blockIdx.x, h = blockIdx.y, z = blockIdx.z;
    const int b = z & 3, branch = z >> 2;
    const bf16* Q  = branch ? Q2 : Q1;
    const bf16* Km = branch ? K2 : K1;
    const bf16* Vt = branch ? V2 : V1;
    bf16*       Yo = branch ? Y2 : Y1;

    const int t = threadIdx.x;
    const int wave = t >> 6, lane = t & 63;
    const int l32 = lane & 31, hi = lane >> 5;
    const int sr = t >> 3, sb = t & 7;          // sr 0..31, sb 0..7

    const int qrow0 = qt * 128 + wave * 32;     // this wave's 32 q rows

    // Q B-frags for the whole loop: qf[ksd] -> Q[qrow0+l32][ksd*16+hi*8 ..+7]
    short8 qf[4];
    {
        const bf16* qptr = Q + (size_t)(b * Nn + qrow0 + l32) * C1 + h * HD + hi * 8;
        #pragma unroll
        for (int ksd = 0; ksd < 4; ++ksd)
            qf[ksd] = *(const short8*)(qptr + ksd * 16);
    }

    f32x16 o[2];                       // [db] PV accumulators
    o[0] = (f32x16){0.f,0.f,0.f,0.f,0.f,0.f,0.f,0.f,0.f,0.f,0.f,0.f,0.f,0.f,0.f,0.f};
    o[1] = o[0];
    float lsum = 0.f;

    const bf16* Kbase = Km + (size_t)b * Nn * C1 + h * HD;
    const bf16* Vbase = Vt + (size_t)(b * Hh + h) * 64 * Nn;

    // register prefetch of the first k-tile staging data
    short8 rk0 = *(const short8*)(Kbase + (size_t)sr * C1 + sb * 8);
    short8 rk1 = *(const short8*)(Kbase + (size_t)(sr + 32) * C1 + sb * 8);
    short8 rv0 = *(const short8*)(Vbase + (size_t)sr * Nn + sb * 8);
    short8 rv1 = *(const short8*)(Vbase + (size_t)(sr + 32) * Nn + sb * 8);

    const int NT = Nn / 64;
    for (int kt = 0; kt < NT; ++kt) {
        __syncthreads();                         // prior iter's readers done
        *(short8*)&lk[swz(sr, sb)]      = rk0;
        *(short8*)&lk[swz(sr + 32, sb)] = rk1;
        *(short8*)&lv[swz(sr, sb)]      = rv0;
        *(short8*)&lv[swz(sr + 32, sb)] = rv1;
        __syncthreads();
        if (kt + 1 < NT) {                       // prefetch next tile; overlaps compute
            const int kn = (kt + 1) * 64;
            rk0 = *(const short8*)(Kbase + (size_t)(kn + sr) * C1 + sb * 8);
            rk1 = *(const short8*)(Kbase + (size_t)(kn + sr + 32) * C1 + sb * 8);
            rv0 = *(const short8*)(Vbase + (size_t)sr * Nn + kn + sb * 8);
            rv1 = *(const short8*)(Vbase + (size_t)(sr + 32) * Nn + kn + sb * 8);
        }

        #pragma unroll
        for (int kb = 0; kb < 2; ++kb) {
            // K a-frags (row k = kb*32 + l32, d = ksd*16 + hi*8)
            short8 ka[4];
            #pragma unroll
            for (int ksd = 0; ksd < 4; ++ksd)
                ka[ksd] = *(const short8*)&lk[swz(kb * 32 + l32, ksd * 2 + hi)];

            // S^T for this wave's 32 q: s[r] = S[k = crow(r,hi)][q = l32]
            f32x16 s = (f32x16){0.f,0.f,0.f,0.f,0.f,0.f,0.f,0.f,0.f,0.f,0.f,0.f,0.f,0.f,0.f,0.f};
            #pragma unroll
            for (int ksd = 0; ksd < 4; ++ksd)
                s = __builtin_amdgcn_mfma_f32_32x32x16_bf16(ka[ksd], qf[ksd], s, 0, 0, 0);

            float p[16];
            #pragma unroll
            for (int r = 0; r < 16; ++r) p[r] = fexp2(s[r]);
            lsum += (((p[0]+p[1])+(p[2]+p[3])) + ((p[4]+p[5])+(p[6]+p[7])))
                  + (((p[8]+p[9])+(p[10]+p[11])) + ((p[12]+p[13])+(p[14]+p[15])));

            // P -> bf16 A-frags in-register
            short8 pa[2];
            {
                unsigned d0 = cvtpk(p[0],  p[1]),  d2 = cvtpk(p[4],  p[5]);
                plswap(d0, d2);
                unsigned d1 = cvtpk(p[2],  p[3]),  d3 = cvtpk(p[6],  p[7]);
                plswap(d1, d3);
                pa[0] = mk8(d0, d1, d2, d3);
                unsigned e0 = cvtpk(p[8],  p[9]),  e2 = cvtpk(p[12], p[13]);
                plswap(e0, e2);
                unsigned e1 = cvtpk(p[10], p[11]), e3 = cvtpk(p[14], p[15]);
                plswap(e1, e3);
                pa[1] = mk8(e0, e1, e2, e3);
            }

            // O += P V
            #pragma unroll
            for (int ks = 0; ks < 2; ++ks) {
                #pragma unroll
                for (int db = 0; db < 2; ++db) {
                    short8 bv = *(const short8*)&lv[swz(db * 32 + l32, kb * 4 + ks * 2 + hi)];
                    o[db] = __builtin_amdgcn_mfma_f32_32x32x16_bf16(pa[ks], bv, o[db], 0, 0, 0);
                }
            }
        }
    }

    // epilogue: complete row sum across hi halves, redistribute to C/D rows, store
    {
        float l = lsum + __shfl_xor(lsum, 32, 64);   // row sum for q = l32
        float inv = 1.0f / l;
        #pragma unroll
        for (int r = 0; r < 16; ++r) {
            const int qr = (r & 3) + 8 * (r >> 2) + 4 * hi;  // C/D row for this reg
            float invr = __shfl(inv, qr, 64);
            size_t row = (size_t)(b * Nn + qrow0 + qr);
            #pragma unroll
            for (int db = 0; db < 2; ++db)
                Yo[row * C1 + h * HD + db * 32 + l32] = __float2bfloat16(o[db][r] * invr);
        }
    }
}

extern "C" void kernel_launch(void* const* d_in, const int* in_sizes, int n_in,
                              void* d_out, int out_size, void* d_ws, size_t ws_size,
                              hipStream_t stream)
{
    const float* x1   = (const float*)d_in[0];
    const float* x2   = (const float*)d_in[1];
    const float* q1w  = (const float*)d_in[2];
    const float* q2w  = (const float*)d_in[3];
    const float* kv1w = (const float*)d_in[4];
    const float* kv2w = (const float*)d_in[5];
    const float* p1w  = (const float*)d_in[6];
    const float* p1b  = (const float*)d_in[7];
    const float* p2w  = (const float*)d_in[8];
    const float* p2b  = (const float*)d_in[9];
    float* out = (float*)d_out;

    bf16* ws = (bf16*)d_ws;
    size_t o = 0;
    bf16* x1b  = ws + o; o += (size_t)Mm * C1;
    bf16* x2b  = ws + o; o += (size_t)Mm * C2;
    bf16* wq1  = ws + o; o += C1 * C1;
    bf16* wq2  = ws + o; o += C1 * C2;
    bf16* wkv1 = ws + o; o += 2 * C1 * C2;
    bf16* wkv2 = ws + o; o += 2 * C1 * C1;
    bf16* wp1  = ws + o; o += C1 * C1;
    bf16* wp2  = ws + o; o += C1 * C1;
    bf16* Q1   = ws + o; o += (size_t)Mm * C1;
    bf16* K1   = ws + o; o += (size_t)Mm * C1;
    bf16* V1t  = ws + o; o += (size_t)Mm * C1;      // [B,H,64,N]
    bf16* Q2   = ws + o; o += (size_t)Mm * C1;
    bf16* K2   = ws + o; o += (size_t)Mm * C1;
    bf16* V2t  = ws + o; o += (size_t)Mm * C1;
    bf16* Y1   = ws + o; o += (size_t)Mm * C1;
    bf16* Y2   = ws + o; o += (size_t)Mm * C1;
    (void)ws_size; (void)in_sizes; (void)n_in; (void)out_size;

    // one convert launch for all 8 fp32->bf16 tensors
    CvtArgs ca;
    ca.s[0] = x1;   ca.d[0] = x1b;  int n0 = Mm * C1;
    ca.s[1] = x2;   ca.d[1] = x2b;  int n1 = Mm * C2;
    ca.s[2] = q1w;  ca.d[2] = wq1;  int n2 = C1 * C1;
    ca.s[3] = q2w;  ca.d[3] = wq2;  int n3 = C1 * C2;
    ca.s[4] = kv1w; ca.d[4] = wkv1; int n4 = 2 * C1 * C2;
    ca.s[5] = kv2w; ca.d[5] = wkv2; int n5 = 2 * C1 * C1;
    ca.s[6] = p1w;  ca.d[6] = wp1;  int n6 = C1 * C1;
    ca.s[7] = p2w;  ca.d[7] = wp2;  int n7 = C1 * C1;
    int ns[8] = {n0, n1, n2, n3, n4, n5, n6, n7};
    ca.off[0] = 0;
    for (int i = 0; i < 8; ++i) ca.off[i + 1] = ca.off[i] + ns[i];
    int total = ca.off[8];
    cvt_all<<<dim3((total / 4 + 255) / 256), 256, 0, stream>>>(ca);

    const float QS = 0.125f * 1.4426950408889634f;   // scale * log2(e), folded into Q

    // fused Q/KV projections: both input tensors in ONE launch (grid 128 x 30)
    // set0 (by 0-14):  x1b, K=320: q1 -> Q1, kv2 -> K2,V2t
    // set1 (by 15-29): x2b, K=256: q2 -> Q2, kv1 -> K1,V1t
    gemm_proj<<<dim3(Mm / 128, 30), 256, 0, stream>>>(
        x1b, wq1, wkv2, x2b, wq2, wkv1, QS,
        Q1, K2, V2t, Q2, K1, V1t);

    // attention, both branches in one launch; 128 q-rows per block
    // (4 waves x 32 q), grid = 32 x 5 x 8 = 1280 blocks, 5120 waves
    flash_kernel<<<dim3(Nn / 128, Hh, 2 * Bb), 256, 0, stream>>>(Q1, K1, V1t, Y1, Q2, K2, V2t, Y2);

    // fused output projections (bias + concat layout), z = branch
    gemm_out<<<dim3(Mm / 128, C1 / 64, 2), 256, 0, stream>>>(Y1, wp1, p1b, Y2, wp2, p2b, out);
}

// Round 8
// 352.200 us; speedup vs baseline: 1.0351x; 1.0351x over previous
//
#include <hip/hip_runtime.h>
#include <hip/hip_bf16.h>

#define Bb 4
#define Nn 4096
#define C1 320
#define C2 256
#define Hh 5
#define HD 64
#define Mm (Bb*Nn)   // 16384

using bf16 = __hip_bfloat16;
typedef __attribute__((ext_vector_type(8))) short  short8;   // 8 bf16 = one MFMA A/B frag
typedef __attribute__((ext_vector_type(4))) short  short4_;
typedef __attribute__((ext_vector_type(4))) float  f32x4;    // 16x16 MFMA C/D frag
typedef __attribute__((ext_vector_type(16))) float f32x16;   // 32x32 MFMA C/D frag
typedef __attribute__((ext_vector_type(2)))  float f32x2;

__device__ __forceinline__ short f2s(float f) {
    bf16 h = __float2bfloat16(f);
    short s;
    __builtin_memcpy(&s, &h, 2);
    return s;
}

__device__ __forceinline__ float fexp2(float x) {
#if __has_builtin(__builtin_amdgcn_exp2f)
    return __builtin_amdgcn_exp2f(x);
#else
    return exp2f(x);
#endif
}

// XOR-swizzled LDS tile addressing, 64-elem rows (8 blocks of 8 bf16 = 16B).
__device__ __forceinline__ int swz(int row, int bb) {
    return row * 64 + ((bb ^ (row & 7)) << 3);
}
// 128-elem rows (16 blocks); XOR stays within each 8-block half -> bijective.
__device__ __forceinline__ int swz16(int row, int bb) {
    return row * 128 + ((bb ^ (row & 7)) << 3);
}

// pack two f32 -> one dword of 2 bf16 (src0 -> low half)
__device__ __forceinline__ unsigned cvtpk(float lo, float hi) {
    unsigned r;
    asm("v_cvt_pk_bf16_f32 %0, %1, %2" : "=v"(r) : "v"(lo), "v"(hi));
    return r;
}

// packed dual-f32 add (VOP3P)
__device__ __forceinline__ f32x2 pkadd(f32x2 a, f32x2 b) {
    f32x2 d;
    asm("v_pk_add_f32 %0, %1, %2" : "=v"(d) : "v"(a), "v"(b));
    return d;
}

// swap: a[lanes 32..63] <- b[lanes 0..31]; b[lanes 0..31] <- a[lanes 32..63]
__device__ __forceinline__ void plswap(unsigned &a, unsigned &b) {
#if __has_builtin(__builtin_amdgcn_permlane32_swap)
    auto r = __builtin_amdgcn_permlane32_swap(a, b, false, false);
    a = r[0]; b = r[1];
#else
    asm("v_permlane32_swap_b32 %0, %1" : "+v"(a), "+v"(b));
#endif
}

__device__ __forceinline__ short8 mk8(unsigned d0, unsigned d1, unsigned d2, unsigned d3) {
    union { unsigned u[4]; short8 s; } u;
    u.u[0] = d0; u.u[1] = d1; u.u[2] = d2; u.u[3] = d3;
    return u.s;
}

// ---------------- fp32 -> bf16 convert, all 8 tensors in one launch ----------------
struct CvtArgs {
    const float* s[8];
    bf16* d[8];
    int off[9];   // cumulative offsets, off[8] = total
};

__global__ void cvt_all(CvtArgs a) {
    int i = (blockIdx.x * blockDim.x + threadIdx.x) * 4;
    if (i >= a.off[8]) return;
    int seg = 0;
    #pragma unroll
    for (int k = 1; k < 8; ++k) seg += (i >= a.off[k]);
    int j = i - a.off[seg];
    float4 v = *(const float4*)(a.s[seg] + j);
    short4_ o = { f2s(v.x), f2s(v.y), f2s(v.z), f2s(v.w) };
    *(short4_*)(a.d[seg] + j) = o;
}

// ---------------- fused projection GEMM: 128x64 tile, both inputs in one launch --------
__global__ __launch_bounds__(256) void gemm_proj(
    const bf16* __restrict__ A1, const bf16* __restrict__ Wq1, const bf16* __restrict__ Wkv1,
    const bf16* __restrict__ A2, const bf16* __restrict__ Wq2, const bf16* __restrict__ Wkv2,
    float qs,
    bf16* __restrict__ Qo1, bf16* __restrict__ Ko1, bf16* __restrict__ Vo1,
    bf16* __restrict__ Qo2, bf16* __restrict__ Ko2, bf16* __restrict__ Vo2)
{
    __shared__ bf16 la[128 * 64];
    __shared__ bf16 lw[64 * 64];
    const int m0 = blockIdx.x * 128;
    const int by = blockIdx.y;
    const int g = (by >= 15);
    const int yy = by - 15 * g;
    const int K = g ? C2 : C1;
    const bf16* A = g ? A2 : A1;
    const bool isq = yy < 5;
    const bf16* W = isq ? (g ? Wq2 : Wq1) : (g ? Wkv2 : Wkv1);
    bf16* Qo = g ? Qo2 : Qo1;
    bf16* Ko = g ? Ko2 : Ko1;
    bf16* Vo = g ? Vo2 : Vo1;
    const int n0 = (isq ? yy : yy - 5) * 64;
    const int t = threadIdx.x;
    const int wave = t >> 6, lane = t & 63, l16 = lane & 15, quad = lane >> 4;
    const int sr = t >> 3, sb = t & 7;      // sr 0..31, sb 0..7

    f32x4 acc[2][4];
    #pragma unroll
    for (int mf = 0; mf < 2; ++mf)
        #pragma unroll
        for (int nt = 0; nt < 4; ++nt) acc[mf][nt] = {0.f,0.f,0.f,0.f};

    const int nk = K >> 6;
    const bf16* ap = A + (size_t)(m0 + sr) * K + sb * 8;
    const bf16* wp = W + (size_t)(n0 + sr) * K + sb * 8;
    short8 ra0 = *(const short8*)ap;
    short8 ra1 = *(const short8*)(ap + (size_t)32 * K);
    short8 ra2 = *(const short8*)(ap + (size_t)64 * K);
    short8 ra3 = *(const short8*)(ap + (size_t)96 * K);
    short8 rw0 = *(const short8*)wp;
    short8 rw1 = *(const short8*)(wp + (size_t)32 * K);

    for (int kt = 0; kt < nk; ++kt) {
        __syncthreads();
        *(short8*)&la[swz(sr,      sb)] = ra0;
        *(short8*)&la[swz(sr + 32, sb)] = ra1;
        *(short8*)&la[swz(sr + 64, sb)] = ra2;
        *(short8*)&la[swz(sr + 96, sb)] = ra3;
        *(short8*)&lw[swz(sr,      sb)] = rw0;
        *(short8*)&lw[swz(sr + 32, sb)] = rw1;
        __syncthreads();
        if (kt + 1 < nk) {
            ap += 64; wp += 64;
            ra0 = *(const short8*)ap;
            ra1 = *(const short8*)(ap + (size_t)32 * K);
            ra2 = *(const short8*)(ap + (size_t)64 * K);
            ra3 = *(const short8*)(ap + (size_t)96 * K);
            rw0 = *(const short8*)wp;
            rw1 = *(const short8*)(wp + (size_t)32 * K);
        }
        const int arow = wave * 32 + l16;
        short8 a00 = *(const short8*)&la[swz(arow,      quad)];
        short8 a01 = *(const short8*)&la[swz(arow,      quad + 4)];
        short8 a10 = *(const short8*)&la[swz(arow + 16, quad)];
        short8 a11 = *(const short8*)&la[swz(arow + 16, quad + 4)];
        #pragma unroll
        for (int nt = 0; nt < 4; ++nt) {
            const int brow = nt * 16 + l16;
            short8 b0 = *(const short8*)&lw[swz(brow, quad)];
            short8 b1 = *(const short8*)&lw[swz(brow, quad + 4)];
            acc[0][nt] = __builtin_amdgcn_mfma_f32_16x16x32_bf16(a00, b0, acc[0][nt], 0, 0, 0);
            acc[0][nt] = __builtin_amdgcn_mfma_f32_16x16x32_bf16(a01, b1, acc[0][nt], 0, 0, 0);
            acc[1][nt] = __builtin_amdgcn_mfma_f32_16x16x32_bf16(a10, b0, acc[1][nt], 0, 0, 0);
            acc[1][nt] = __builtin_amdgcn_mfma_f32_16x16x32_bf16(a11, b1, acc[1][nt], 0, 0, 0);
        }
    }

    const bool isv = !isq && n0 >= C1;     // whole block is V-part or not
    #pragma unroll
    for (int mf = 0; mf < 2; ++mf) {
        const int mrow = m0 + wave * 32 + mf * 16 + quad * 4;
        if (isq) {
            #pragma unroll
            for (int nt = 0; nt < 4; ++nt) {
                int col = n0 + nt * 16 + l16;
                #pragma unroll
                for (int r = 0; r < 4; ++r)
                    Qo[(size_t)(mrow + r) * C1 + col] = __float2bfloat16(acc[mf][nt][r] * qs);
            }
        } else if (!isv) {
            #pragma unroll
            for (int nt = 0; nt < 4; ++nt) {
                int col = n0 + nt * 16 + l16;
                #pragma unroll
                for (int r = 0; r < 4; ++r)
                    Ko[(size_t)(mrow + r) * C1 + col] = __float2bfloat16(acc[mf][nt][r]);
            }
        } else {
            #pragma unroll
            for (int nt = 0; nt < 4; ++nt) {
                int col = n0 + nt * 16 + l16 - C1;
                int h = col >> 6, d = col & 63;
                #pragma unroll
                for (int r = 0; r < 4; ++r) {
                    int m = mrow + r;
                    int b = m >> 12, n = m & (Nn - 1);
                    Vo[((size_t)(b * Hh + h) * 64 + d) * Nn + n] = __float2bfloat16(acc[mf][nt][r]);
                }
            }
        }
    }
}

// ---------------- fused output projections: 128x64 tile, z = branch ----------------
__global__ __launch_bounds__(256) void gemm_out(
    const bf16* __restrict__ Y1, const bf16* __restrict__ Wp1, const float* __restrict__ B1,
    const bf16* __restrict__ Y2, const bf16* __restrict__ Wp2, const float* __restrict__ B2,
    float* __restrict__ Of)
{
    __shared__ bf16 la[128 * 64];
    __shared__ bf16 lw[64 * 64];
    const int zz = blockIdx.z;
    const bf16* A = zz ? Y2 : Y1;
    const bf16* W = zz ? Wp2 : Wp1;
    const float* bias = zz ? B2 : B1;
    const int ooff = zz ? C1 : 0;
    const int m0 = blockIdx.x * 128, n0 = blockIdx.y * 64;
    const int t = threadIdx.x;
    const int wave = t >> 6, lane = t & 63, l16 = lane & 15, quad = lane >> 4;
    const int sr = t >> 3, sb = t & 7;
    const int K = C1;

    f32x4 acc[2][4];
    #pragma unroll
    for (int mf = 0; mf < 2; ++mf)
        #pragma unroll
        for (int nt = 0; nt < 4; ++nt) acc[mf][nt] = {0.f,0.f,0.f,0.f};

    const int nk = K >> 6;
    const bf16* ap = A + (size_t)(m0 + sr) * K + sb * 8;
    const bf16* wp = W + (size_t)(n0 + sr) * K + sb * 8;
    short8 ra0 = *(const short8*)ap;
    short8 ra1 = *(const short8*)(ap + (size_t)32 * K);
    short8 ra2 = *(const short8*)(ap + (size_t)64 * K);
    short8 ra3 = *(const short8*)(ap + (size_t)96 * K);
    short8 rw0 = *(const short8*)wp;
    short8 rw1 = *(const short8*)(wp + (size_t)32 * K);

    for (int kt = 0; kt < nk; ++kt) {
        __syncthreads();
        *(short8*)&la[swz(sr,      sb)] = ra0;
        *(short8*)&la[swz(sr + 32, sb)] = ra1;
        *(short8*)&la[swz(sr + 64, sb)] = ra2;
        *(short8*)&la[swz(sr + 96, sb)] = ra3;
        *(short8*)&lw[swz(sr,      sb)] = rw0;
        *(short8*)&lw[swz(sr + 32, sb)] = rw1;
        __syncthreads();
        if (kt + 1 < nk) {
            ap += 64; wp += 64;
            ra0 = *(const short8*)ap;
            ra1 = *(const short8*)(ap + (size_t)32 * K);
            ra2 = *(const short8*)(ap + (size_t)64 * K);
            ra3 = *(const short8*)(ap + (size_t)96 * K);
            rw0 = *(const short8*)wp;
            rw1 = *(const short8*)(wp + (size_t)32 * K);
        }
        const int arow = wave * 32 + l16;
        short8 a00 = *(const short8*)&la[swz(arow,      quad)];
        short8 a01 = *(const short8*)&la[swz(arow,      quad + 4)];
        short8 a10 = *(const short8*)&la[swz(arow + 16, quad)];
        short8 a11 = *(const short8*)&la[swz(arow + 16, quad + 4)];
        #pragma unroll
        for (int nt = 0; nt < 4; ++nt) {
            const int brow = nt * 16 + l16;
            short8 b0 = *(const short8*)&lw[swz(brow, quad)];
            short8 b1 = *(const short8*)&lw[swz(brow, quad + 4)];
            acc[0][nt] = __builtin_amdgcn_mfma_f32_16x16x32_bf16(a00, b0, acc[0][nt], 0, 0, 0);
            acc[0][nt] = __builtin_amdgcn_mfma_f32_16x16x32_bf16(a01, b1, acc[0][nt], 0, 0, 0);
            acc[1][nt] = __builtin_amdgcn_mfma_f32_16x16x32_bf16(a10, b0, acc[1][nt], 0, 0, 0);
            acc[1][nt] = __builtin_amdgcn_mfma_f32_16x16x32_bf16(a11, b1, acc[1][nt], 0, 0, 0);
        }
    }

    #pragma unroll
    for (int mf = 0; mf < 2; ++mf) {
        const int mrow = m0 + wave * 32 + mf * 16 + quad * 4;
        #pragma unroll
        for (int nt = 0; nt < 4; ++nt) {
            int col = n0 + nt * 16 + l16;
            float bv = bias[col];
            #pragma unroll
            for (int r = 0; r < 4; ++r)
                Of[(size_t)(mrow + r) * 640 + ooff + col] = acc[mf][nt][r] + bv;
        }
    }
}

// ---------------- flash attention, both branches in one launch ----------------
// R1 structure (4 waves x 64 q, qb-amortized LDS reads) with KVBLK=128:
// K tile [128 k][64 d] (16KB), V tile [64 d][128 k] (16KB) -> barriers and
// staging-loop overhead halved (32 iters x 2 barriers vs 64 x 2).
// Staging pointers incremental; lsum via v_pk_add_f32 tree.
// Everything else identical to R1: swapped QK^T 32x32 MFMA (lane holds P-row
// slice: q = lane&31, k = (r&3)+8*(r>>2)+4*hi), in-register P->bf16 via
// cvt_pk + permlane32_swap, fixed m=0 softmax (Q pre-scaled by 0.125*log2e).
__global__ __launch_bounds__(256, 2) void flash_kernel(
    const bf16* __restrict__ Q1, const bf16* __restrict__ K1,
    const bf16* __restrict__ V1, bf16* __restrict__ Y1,
    const bf16* __restrict__ Q2, const bf16* __restrict__ K2,
    const bf16* __restrict__ V2, bf16* __restrict__ Y2)
{
    __shared__ bf16 lk[128 * 64];       // K tile [k][d], swizzled (64-elem rows)
    __shared__ bf16 lv[64 * 128];       // V tile [d][k], swizzled (128-elem rows)
    const int qt = blockIdx.x, h = blockIdx.y, z = blockIdx.z;
    const int b = z & 3, branch = z >> 2;
    const bf16* Q  = branch ? Q2 : Q1;
    const bf16* Km = branch ? K2 : K1;
    const bf16* Vt = branch ? V2 : V1;
    bf16*       Yo = branch ? Y2 : Y1;

    const int t = threadIdx.x;
    const int wave = t >> 6, lane = t & 63;
    const int l32 = lane & 31, hi = lane >> 5;
    const int sr = t >> 3, sb = t & 7;          // sr 0..31, sb 0..7

    const int qrow0 = qt * 256 + wave * 64;     // this wave's 64 q rows

    // Q B-frags for the whole loop: [qb][ksd] -> Q[qrow0+qb*32+l32][ksd*16+hi*8 ..+7]
    short8 qf[2][4];
    #pragma unroll
    for (int qb = 0; qb < 2; ++qb) {
        const bf16* qptr = Q + (size_t)(b * Nn + qrow0 + qb * 32 + l32) * C1 + h * HD + hi * 8;
        #pragma unroll
        for (int ksd = 0; ksd < 4; ++ksd)
            qf[qb][ksd] = *(const short8*)(qptr + ksd * 16);
    }

    f32x16 o[2][2];                    // [qb][db] PV accumulators
    #pragma unroll
    for (int qb = 0; qb < 2; ++qb)
        #pragma unroll
        for (int db = 0; db < 2; ++db)
            o[qb][db] = (f32x16){0.f,0.f,0.f,0.f,0.f,0.f,0.f,0.f,0.f,0.f,0.f,0.f,0.f,0.f,0.f,0.f};
    float lsum[2] = {0.f, 0.f};

    const bf16* Kbase = Km + (size_t)b * Nn * C1 + h * HD;
    const bf16* Vbase = Vt + (size_t)(b * Hh + h) * 64 * Nn;

    // incremental staging pointers; register prefetch of first 128-k tile
    const bf16* kp0 = Kbase + (size_t)sr * C1 + sb * 8;           // rows sr + 32*i
    const bf16* vp0 = Vbase + (size_t)sr * Nn + sb * 8;           // d rows sr, sr+32; k blocks sb, sb+8
    short8 rk0 = *(const short8*)kp0;
    short8 rk1 = *(const short8*)(kp0 + (size_t)32 * C1);
    short8 rk2 = *(const short8*)(kp0 + (size_t)64 * C1);
    short8 rk3 = *(const short8*)(kp0 + (size_t)96 * C1);
    short8 rv0 = *(const short8*)vp0;
    short8 rv1 = *(const short8*)(vp0 + 64);
    short8 rv2 = *(const short8*)(vp0 + (size_t)32 * Nn);
    short8 rv3 = *(const short8*)(vp0 + (size_t)32 * Nn + 64);

    const int NT = Nn / 128;
    for (int kt = 0; kt < NT; ++kt) {
        __syncthreads();                         // prior iter's readers done
        *(short8*)&lk[swz(sr,      sb)] = rk0;
        *(short8*)&lk[swz(sr + 32, sb)] = rk1;
        *(short8*)&lk[swz(sr + 64, sb)] = rk2;
        *(short8*)&lk[swz(sr + 96, sb)] = rk3;
        *(short8*)&lv[swz16(sr,      sb)]     = rv0;
        *(short8*)&lv[swz16(sr,      sb + 8)] = rv1;
        *(short8*)&lv[swz16(sr + 32, sb)]     = rv2;
        *(short8*)&lv[swz16(sr + 32, sb + 8)] = rv3;
        __syncthreads();
        if (kt + 1 < NT) {                       // prefetch next tile; overlaps compute
            kp0 += (size_t)128 * C1;
            vp0 += 128;
            rk0 = *(const short8*)kp0;
            rk1 = *(const short8*)(kp0 + (size_t)32 * C1);
            rk2 = *(const short8*)(kp0 + (size_t)64 * C1);
            rk3 = *(const short8*)(kp0 + (size_t)96 * C1);
            rv0 = *(const short8*)vp0;
            rv1 = *(const short8*)(vp0 + 64);
            rv2 = *(const short8*)(vp0 + (size_t)32 * Nn);
            rv3 = *(const short8*)(vp0 + (size_t)32 * Nn + 64);
        }

        #pragma unroll
        for (int kb = 0; kb < 4; ++kb) {
            // K a-frags (row k = kb*32 + l32, d = ksd*16 + hi*8), reused by both qb
            short8 ka[4];
            #pragma unroll
            for (int ksd = 0; ksd < 4; ++ksd)
                ka[ksd] = *(const short8*)&lk[swz(kb * 32 + l32, ksd * 2 + hi)];

            short8 pa[2][2];   // [qb][ks] PV A-frags, built fully in-register
            #pragma unroll
            for (int qb = 0; qb < 2; ++qb) {
                f32x16 s = (f32x16){0.f,0.f,0.f,0.f,0.f,0.f,0.f,0.f,0.f,0.f,0.f,0.f,0.f,0.f,0.f,0.f};
                #pragma unroll
                for (int ksd = 0; ksd < 4; ++ksd)
                    s = __builtin_amdgcn_mfma_f32_32x32x16_bf16(ka[ksd], qf[qb][ksd], s, 0, 0, 0);
                // p[r] = P[q = l32][k = (r&3) + 8*(r>>2) + 4*hi] (within this kb)
                float p[16];
                #pragma unroll
                for (int r = 0; r < 16; ++r) p[r] = fexp2(s[r]);
                // lsum via packed-f32 adds: 7 pk_add + 2 scalar
                {
                    f32x2 t0 = pkadd((f32x2){p[0], p[1]},  (f32x2){p[2], p[3]});
                    f32x2 t1 = pkadd((f32x2){p[4], p[5]},  (f32x2){p[6], p[7]});
                    f32x2 t2 = pkadd((f32x2){p[8], p[9]},  (f32x2){p[10], p[11]});
                    f32x2 t3 = pkadd((f32x2){p[12], p[13]},(f32x2){p[14], p[15]});
                    t0 = pkadd(t0, t1);
                    t2 = pkadd(t2, t3);
                    t0 = pkadd(t0, t2);
                    lsum[qb] += t0.x + t0.y;
                }
                // ks=0 (k 0..15): dw0/dw2 from one swap, dw1/dw3 from the other
                unsigned d0 = cvtpk(p[0],  p[1]),  d2 = cvtpk(p[4],  p[5]);
                plswap(d0, d2);
                unsigned d1 = cvtpk(p[2],  p[3]),  d3 = cvtpk(p[6],  p[7]);
                plswap(d1, d3);
                pa[qb][0] = mk8(d0, d1, d2, d3);
                // ks=1 (k 16..31)
                unsigned e0 = cvtpk(p[8],  p[9]),  e2 = cvtpk(p[12], p[13]);
                plswap(e0, e2);
                unsigned e1 = cvtpk(p[10], p[11]), e3 = cvtpk(p[14], p[15]);
                plswap(e1, e3);
                pa[qb][1] = mk8(e0, e1, e2, e3);
            }

            // O += P V ; each V b-frag read once, reused by both qb
            #pragma unroll
            for (int ks = 0; ks < 2; ++ks) {
                #pragma unroll
                for (int db = 0; db < 2; ++db) {
                    short8 bv = *(const short8*)&lv[swz16(db * 32 + l32, kb * 4 + ks * 2 + hi)];
                    o[0][db] = __builtin_amdgcn_mfma_f32_32x32x16_bf16(pa[0][ks], bv, o[0][db], 0, 0, 0);
                    o[1][db] = __builtin_amdgcn_mfma_f32_32x32x16_bf16(pa[1][ks], bv, o[1][db], 0, 0, 0);
                }
            }
        }
    }

    // epilogue: complete row sums across hi halves, redistribute to C/D rows, store
    #pragma unroll
    for (int qb = 0; qb < 2; ++qb) {
        float l = lsum[qb] + __shfl_xor(lsum[qb], 32, 64);  // row sum for q = qb*32 + l32
        float inv = 1.0f / l;
        #pragma unroll
        for (int r = 0; r < 16; ++r) {
            const int qr = (r & 3) + 8 * (r >> 2) + 4 * hi;  // C/D row for this reg
            float invr = __shfl(inv, qr, 64);
            size_t row = (size_t)(b * Nn + qrow0 + qb * 32 + qr);
            #pragma unroll
            for (int db = 0; db < 2; ++db)
                Yo[row * C1 + h * HD + db * 32 + l32] = __float2bfloat16(o[qb][db][r] * invr);
        }
    }
}

extern "C" void kernel_launch(void* const* d_in, const int* in_sizes, int n_in,
                              void* d_out, int out_size, void* d_ws, size_t ws_size,
                              hipStream_t stream)
{
    const float* x1   = (const float*)d_in[0];
    const float* x2   = (const float*)d_in[1];
    const float* q1w  = (const float*)d_in[2];
    const float* q2w  = (const float*)d_in[3];
    const float* kv1w = (const float*)d_in[4];
    const float* kv2w = (const float*)d_in[5];
    const float* p1w  = (const float*)d_in[6];
    const float* p1b  = (const float*)d_in[7];
    const float* p2w  = (const float*)d_in[8];
    const float* p2b  = (const float*)d_in[9];
    float* out = (float*)d_out;

    bf16* ws = (bf16*)d_ws;
    size_t o = 0;
    bf16* x1b  = ws + o; o += (size_t)Mm * C1;
    bf16* x2b  = ws + o; o += (size_t)Mm * C2;
    bf16* wq1  = ws + o; o += C1 * C1;
    bf16* wq2  = ws + o; o += C1 * C2;
    bf16* wkv1 = ws + o; o += 2 * C1 * C2;
    bf16* wkv2 = ws + o; o += 2 * C1 * C1;
    bf16* wp1  = ws + o; o += C1 * C1;
    bf16* wp2  = ws + o; o += C1 * C1;
    bf16* Q1   = ws + o; o += (size_t)Mm * C1;
    bf16* K1   = ws + o; o += (size_t)Mm * C1;
    bf16* V1t  = ws + o; o += (size_t)Mm * C1;      // [B,H,64,N]
    bf16* Q2   = ws + o; o += (size_t)Mm * C1;
    bf16* K2   = ws + o; o += (size_t)Mm * C1;
    bf16* V2t  = ws + o; o += (size_t)Mm * C1;
    bf16* Y1   = ws + o; o += (size_t)Mm * C1;
    bf16* Y2   = ws + o; o += (size_t)Mm * C1;
    (void)ws_size; (void)in_sizes; (void)n_in; (void)out_size;

    // one convert launch for all 8 fp32->bf16 tensors
    CvtArgs ca;
    ca.s[0] = x1;   ca.d[0] = x1b;  int n0 = Mm * C1;
    ca.s[1] = x2;   ca.d[1] = x2b;  int n1 = Mm * C2;
    ca.s[2] = q1w;  ca.d[2] = wq1;  int n2 = C1 * C1;
    ca.s[3] = q2w;  ca.d[3] = wq2;  int n3 = C1 * C2;
    ca.s[4] = kv1w; ca.d[4] = wkv1; int n4 = 2 * C1 * C2;
    ca.s[5] = kv2w; ca.d[5] = wkv2; int n5 = 2 * C1 * C1;
    ca.s[6] = p1w;  ca.d[6] = wp1;  int n6 = C1 * C1;
    ca.s[7] = p2w;  ca.d[7] = wp2;  int n7 = C1 * C1;
    int ns[8] = {n0, n1, n2, n3, n4, n5, n6, n7};
    ca.off[0] = 0;
    for (int i = 0; i < 8; ++i) ca.off[i + 1] = ca.off[i] + ns[i];
    int total = ca.off[8];
    cvt_all<<<dim3((total / 4 + 255) / 256), 256, 0, stream>>>(ca);

    const float QS = 0.125f * 1.4426950408889634f;   // scale * log2(e), folded into Q

    // fused Q/KV projections: both input tensors in ONE launch (grid 128 x 30)
    gemm_proj<<<dim3(Mm / 128, 30), 256, 0, stream>>>(
        x1b, wq1, wkv2, x2b, wq2, wkv1, QS,
        Q1, K2, V2t, Q2, K1, V1t);

    // attention, both branches in one launch; 256 q-rows per block (4 waves x 64 q)
    flash_kernel<<<dim3(Nn / 256, Hh, 2 * Bb), 256, 0, stream>>>(Q1, K1, V1t, Y1, Q2, K2, V2t, Y2);

    // fused output projections (bias + concat layout), z = branch
    gemm_out<<<dim3(Mm / 128, C1 / 64, 2), 256, 0, stream>>>(Y1, wp1, p1b, Y2, wp2, p2b, out);
}

// Round 9
// 344.043 us; speedup vs baseline: 1.0597x; 1.0237x over previous
//
#include <hip/hip_runtime.h>
#include <hip/hip_bf16.h>

#define Bb 4
#define Nn 4096
#define C1 320
#define C2 256
#define Hh 5
#define HD 64
#define Mm (Bb*Nn)   // 16384

using bf16 = __hip_bfloat16;
typedef __attribute__((ext_vector_type(8))) short  short8;   // 8 bf16 = one MFMA A/B frag
typedef __attribute__((ext_vector_type(4))) short  short4_;
typedef __attribute__((ext_vector_type(4))) float  f32x4;    // 16x16 MFMA C/D frag
typedef __attribute__((ext_vector_type(16))) float f32x16;   // 32x32 MFMA C/D frag
typedef __attribute__((ext_vector_type(2)))  float f32x2;

__device__ __forceinline__ short f2s(float f) {
    bf16 h = __float2bfloat16(f);
    short s;
    __builtin_memcpy(&s, &h, 2);
    return s;
}

__device__ __forceinline__ float fexp2(float x) {
#if __has_builtin(__builtin_amdgcn_exp2f)
    return __builtin_amdgcn_exp2f(x);
#else
    return exp2f(x);
#endif
}

// XOR-swizzled LDS tile addressing: 64-elem rows, 8 blocks of 8 bf16 (16B).
__device__ __forceinline__ int swz(int row, int bb) {
    return row * 64 + ((bb ^ (row & 7)) << 3);
}

// pack two f32 -> one dword of 2 bf16 (src0 -> low half), RNE (matches __float2bfloat16)
__device__ __forceinline__ unsigned cvtpk(float lo, float hi) {
    unsigned r;
    asm("v_cvt_pk_bf16_f32 %0, %1, %2" : "=v"(r) : "v"(lo), "v"(hi));
    return r;
}

// packed dual-f32 add (VOP3P)
__device__ __forceinline__ f32x2 pkadd(f32x2 a, f32x2 b) {
    f32x2 d;
    asm("v_pk_add_f32 %0, %1, %2" : "=v"(d) : "v"(a), "v"(b));
    return d;
}

// swap: a[lanes 32..63] <- b[lanes 0..31]; b[lanes 0..31] <- a[lanes 32..63]
__device__ __forceinline__ void plswap(unsigned &a, unsigned &b) {
#if __has_builtin(__builtin_amdgcn_permlane32_swap)
    auto r = __builtin_amdgcn_permlane32_swap(a, b, false, false);
    a = r[0]; b = r[1];
#else
    asm("v_permlane32_swap_b32 %0, %1" : "+v"(a), "+v"(b));
#endif
}

__device__ __forceinline__ short8 mk8(unsigned d0, unsigned d1, unsigned d2, unsigned d3) {
    union { unsigned u[4]; short8 s; } u;
    u.u[0] = d0; u.u[1] = d1; u.u[2] = d2; u.u[3] = d3;
    return u.s;
}

// convert 8 consecutive f32 (two float4) -> short8 of bf16
__device__ __forceinline__ short8 cvt8(float4 lo, float4 hi) {
    return mk8(cvtpk(lo.x, lo.y), cvtpk(lo.z, lo.w),
               cvtpk(hi.x, hi.y), cvtpk(hi.z, hi.w));
}

// ---------------- fp32 -> bf16 convert, WEIGHTS ONLY (x converts inside gemm_proj) ----
struct CvtArgs {
    const float* s[6];
    bf16* d[6];
    int off[7];   // cumulative offsets, off[6] = total
};

__global__ void cvt_all(CvtArgs a) {
    int i = (blockIdx.x * blockDim.x + threadIdx.x) * 4;
    if (i >= a.off[6]) return;
    int seg = 0;
    #pragma unroll
    for (int k = 1; k < 6; ++k) seg += (i >= a.off[k]);
    int j = i - a.off[seg];
    float4 v = *(const float4*)(a.s[seg] + j);
    short4_ o = { f2s(v.x), f2s(v.y), f2s(v.z), f2s(v.w) };
    *(short4_*)(a.d[seg] + j) = o;
}

// ---------------- fused projection GEMM: 128x64 tile, both inputs in one launch --------
// A inputs are the ORIGINAL fp32 x1/x2; conversion to bf16 is fused into A-staging.
// by in [0,30): g = by/15 selects input set (0: x1-set K=320, 1: x2-set K=256), yy = by%15.
// yy < 5 : Q-part:  Qo[row*320+col] = bf16(acc * qs)          (W = Wq,  Nout=320)
// yy >= 5: KV-part: col<320 -> Ko[row*320+col] = bf16(acc)    (W = Wkv, Nout=640)
//                   col>=320 -> Vo transposed [B,H,64,N]
__global__ __launch_bounds__(256) void gemm_proj(
    const float* __restrict__ A1, const bf16* __restrict__ Wq1, const bf16* __restrict__ Wkv1,
    const float* __restrict__ A2, const bf16* __restrict__ Wq2, const bf16* __restrict__ Wkv2,
    float qs,
    bf16* __restrict__ Qo1, bf16* __restrict__ Ko1, bf16* __restrict__ Vo1,
    bf16* __restrict__ Qo2, bf16* __restrict__ Ko2, bf16* __restrict__ Vo2)
{
    __shared__ bf16 la[128 * 64];
    __shared__ bf16 lw[64 * 64];
    const int m0 = blockIdx.x * 128;
    const int by = blockIdx.y;
    const int g = (by >= 15);
    const int yy = by - 15 * g;
    const int K = g ? C2 : C1;
    const float* A = g ? A2 : A1;
    const bool isq = yy < 5;
    const bf16* W = isq ? (g ? Wq2 : Wq1) : (g ? Wkv2 : Wkv1);
    bf16* Qo = g ? Qo2 : Qo1;
    bf16* Ko = g ? Ko2 : Ko1;
    bf16* Vo = g ? Vo2 : Vo1;
    const int n0 = (isq ? yy : yy - 5) * 64;
    const int t = threadIdx.x;
    const int wave = t >> 6, lane = t & 63, l16 = lane & 15, quad = lane >> 4;
    const int sr = t >> 3, sb = t & 7;      // sr 0..31, sb 0..7

    f32x4 acc[2][4];
    #pragma unroll
    for (int mf = 0; mf < 2; ++mf)
        #pragma unroll
        for (int nt = 0; nt < 4; ++nt) acc[mf][nt] = {0.f,0.f,0.f,0.f};

    const int nk = K >> 6;
    const float* ap = A + (size_t)(m0 + sr) * K + sb * 8;
    const bf16*  wp = W + (size_t)(n0 + sr) * K + sb * 8;
    float4 fa0 = *(const float4*)ap,                       fa0h = *(const float4*)(ap + 4);
    float4 fa1 = *(const float4*)(ap + (size_t)32 * K),    fa1h = *(const float4*)(ap + (size_t)32 * K + 4);
    float4 fa2 = *(const float4*)(ap + (size_t)64 * K),    fa2h = *(const float4*)(ap + (size_t)64 * K + 4);
    float4 fa3 = *(const float4*)(ap + (size_t)96 * K),    fa3h = *(const float4*)(ap + (size_t)96 * K + 4);
    short8 rw0 = *(const short8*)wp;
    short8 rw1 = *(const short8*)(wp + (size_t)32 * K);

    for (int kt = 0; kt < nk; ++kt) {
        __syncthreads();
        *(short8*)&la[swz(sr,      sb)] = cvt8(fa0, fa0h);
        *(short8*)&la[swz(sr + 32, sb)] = cvt8(fa1, fa1h);
        *(short8*)&la[swz(sr + 64, sb)] = cvt8(fa2, fa2h);
        *(short8*)&la[swz(sr + 96, sb)] = cvt8(fa3, fa3h);
        *(short8*)&lw[swz(sr,      sb)] = rw0;
        *(short8*)&lw[swz(sr + 32, sb)] = rw1;
        __syncthreads();
        if (kt + 1 < nk) {
            ap += 64; wp += 64;
            fa0 = *(const float4*)ap;                    fa0h = *(const float4*)(ap + 4);
            fa1 = *(const float4*)(ap + (size_t)32 * K); fa1h = *(const float4*)(ap + (size_t)32 * K + 4);
            fa2 = *(const float4*)(ap + (size_t)64 * K); fa2h = *(const float4*)(ap + (size_t)64 * K + 4);
            fa3 = *(const float4*)(ap + (size_t)96 * K); fa3h = *(const float4*)(ap + (size_t)96 * K + 4);
            rw0 = *(const short8*)wp;
            rw1 = *(const short8*)(wp + (size_t)32 * K);
        }
        const int arow = wave * 32 + l16;
        short8 a00 = *(const short8*)&la[swz(arow,      quad)];
        short8 a01 = *(const short8*)&la[swz(arow,      quad + 4)];
        short8 a10 = *(const short8*)&la[swz(arow + 16, quad)];
        short8 a11 = *(const short8*)&la[swz(arow + 16, quad + 4)];
        #pragma unroll
        for (int nt = 0; nt < 4; ++nt) {
            const int brow = nt * 16 + l16;
            short8 b0 = *(const short8*)&lw[swz(brow, quad)];
            short8 b1 = *(const short8*)&lw[swz(brow, quad + 4)];
            acc[0][nt] = __builtin_amdgcn_mfma_f32_16x16x32_bf16(a00, b0, acc[0][nt], 0, 0, 0);
            acc[0][nt] = __builtin_amdgcn_mfma_f32_16x16x32_bf16(a01, b1, acc[0][nt], 0, 0, 0);
            acc[1][nt] = __builtin_amdgcn_mfma_f32_16x16x32_bf16(a10, b0, acc[1][nt], 0, 0, 0);
            acc[1][nt] = __builtin_amdgcn_mfma_f32_16x16x32_bf16(a11, b1, acc[1][nt], 0, 0, 0);
        }
    }

    const bool isv = !isq && n0 >= C1;     // whole block is V-part or not
    #pragma unroll
    for (int mf = 0; mf < 2; ++mf) {
        const int mrow = m0 + wave * 32 + mf * 16 + quad * 4;
        if (isq) {
            #pragma unroll
            for (int nt = 0; nt < 4; ++nt) {
                int col = n0 + nt * 16 + l16;
                #pragma unroll
                for (int r = 0; r < 4; ++r)
                    Qo[(size_t)(mrow + r) * C1 + col] = __float2bfloat16(acc[mf][nt][r] * qs);
            }
        } else if (!isv) {
            #pragma unroll
            for (int nt = 0; nt < 4; ++nt) {
                int col = n0 + nt * 16 + l16;
                #pragma unroll
                for (int r = 0; r < 4; ++r)
                    Ko[(size_t)(mrow + r) * C1 + col] = __float2bfloat16(acc[mf][nt][r]);
            }
        } else {
            #pragma unroll
            for (int nt = 0; nt < 4; ++nt) {
                int col = n0 + nt * 16 + l16 - C1;
                int h = col >> 6, d = col & 63;
                #pragma unroll
                for (int r = 0; r < 4; ++r) {
                    int m = mrow + r;
                    int b = m >> 12, n = m & (Nn - 1);
                    Vo[((size_t)(b * Hh + h) * 64 + d) * Nn + n] = __float2bfloat16(acc[mf][nt][r]);
                }
            }
        }
    }
}

// ---------------- fused output projections: 128x64 tile, z = branch ----------------
__global__ __launch_bounds__(256) void gemm_out(
    const bf16* __restrict__ Y1, const bf16* __restrict__ Wp1, const float* __restrict__ B1,
    const bf16* __restrict__ Y2, const bf16* __restrict__ Wp2, const float* __restrict__ B2,
    float* __restrict__ Of)
{
    __shared__ bf16 la[128 * 64];
    __shared__ bf16 lw[64 * 64];
    const int zz = blockIdx.z;
    const bf16* A = zz ? Y2 : Y1;
    const bf16* W = zz ? Wp2 : Wp1;
    const float* bias = zz ? B2 : B1;
    const int ooff = zz ? C1 : 0;
    const int m0 = blockIdx.x * 128, n0 = blockIdx.y * 64;
    const int t = threadIdx.x;
    const int wave = t >> 6, lane = t & 63, l16 = lane & 15, quad = lane >> 4;
    const int sr = t >> 3, sb = t & 7;
    const int K = C1;

    f32x4 acc[2][4];
    #pragma unroll
    for (int mf = 0; mf < 2; ++mf)
        #pragma unroll
        for (int nt = 0; nt < 4; ++nt) acc[mf][nt] = {0.f,0.f,0.f,0.f};

    const int nk = K >> 6;
    const bf16* ap = A + (size_t)(m0 + sr) * K + sb * 8;
    const bf16* wp = W + (size_t)(n0 + sr) * K + sb * 8;
    short8 ra0 = *(const short8*)ap;
    short8 ra1 = *(const short8*)(ap + (size_t)32 * K);
    short8 ra2 = *(const short8*)(ap + (size_t)64 * K);
    short8 ra3 = *(const short8*)(ap + (size_t)96 * K);
    short8 rw0 = *(const short8*)wp;
    short8 rw1 = *(const short8*)(wp + (size_t)32 * K);

    for (int kt = 0; kt < nk; ++kt) {
        __syncthreads();
        *(short8*)&la[swz(sr,      sb)] = ra0;
        *(short8*)&la[swz(sr + 32, sb)] = ra1;
        *(short8*)&la[swz(sr + 64, sb)] = ra2;
        *(short8*)&la[swz(sr + 96, sb)] = ra3;
        *(short8*)&lw[swz(sr,      sb)] = rw0;
        *(short8*)&lw[swz(sr + 32, sb)] = rw1;
        __syncthreads();
        if (kt + 1 < nk) {
            ap += 64; wp += 64;
            ra0 = *(const short8*)ap;
            ra1 = *(const short8*)(ap + (size_t)32 * K);
            ra2 = *(const short8*)(ap + (size_t)64 * K);
            ra3 = *(const short8*)(ap + (size_t)96 * K);
            rw0 = *(const short8*)wp;
            rw1 = *(const short8*)(wp + (size_t)32 * K);
        }
        const int arow = wave * 32 + l16;
        short8 a00 = *(const short8*)&la[swz(arow,      quad)];
        short8 a01 = *(const short8*)&la[swz(arow,      quad + 4)];
        short8 a10 = *(const short8*)&la[swz(arow + 16, quad)];
        short8 a11 = *(const short8*)&la[swz(arow + 16, quad + 4)];
        #pragma unroll
        for (int nt = 0; nt < 4; ++nt) {
            const int brow = nt * 16 + l16;
            short8 b0 = *(const short8*)&lw[swz(brow, quad)];
            short8 b1 = *(const short8*)&lw[swz(brow, quad + 4)];
            acc[0][nt] = __builtin_amdgcn_mfma_f32_16x16x32_bf16(a00, b0, acc[0][nt], 0, 0, 0);
            acc[0][nt] = __builtin_amdgcn_mfma_f32_16x16x32_bf16(a01, b1, acc[0][nt], 0, 0, 0);
            acc[1][nt] = __builtin_amdgcn_mfma_f32_16x16x32_bf16(a10, b0, acc[1][nt], 0, 0, 0);
            acc[1][nt] = __builtin_amdgcn_mfma_f32_16x16x32_bf16(a11, b1, acc[1][nt], 0, 0, 0);
        }
    }

    #pragma unroll
    for (int mf = 0; mf < 2; ++mf) {
        const int mrow = m0 + wave * 32 + mf * 16 + quad * 4;
        #pragma unroll
        for (int nt = 0; nt < 4; ++nt) {
            int col = n0 + nt * 16 + l16;
            float bv = bias[col];
            #pragma unroll
            for (int r = 0; r < 4; ++r)
                Of[(size_t)(mrow + r) * 640 + ooff + col] = acc[mf][nt][r] + bv;
        }
    }
}

// ---------------- flash attention, both branches in one launch ----------------
// Proven R1 structure (best measured: 196 us): 4 waves x 64 q (2 q-blocks of 32),
// KVBLK=64, 16KB swizzled LDS K/V tiles, 2 barriers/kt, register-prefetched
// staging. Swapped QK^T 32x32 MFMA (lane holds P-row slice: q = lane&31,
// k = (r&3)+8*(r>>2)+4*hi); in-register P->bf16 via cvt_pk + permlane32_swap;
// fixed m=0 softmax (Q pre-scaled by 0.125*log2e).
// Only sub-structural changes vs R1: pk_add lsum tree, incremental staging ptrs.
__global__ __launch_bounds__(256, 2) void flash_kernel(
    const bf16* __restrict__ Q1, const bf16* __restrict__ K1,
    const bf16* __restrict__ V1, bf16* __restrict__ Y1,
    const bf16* __restrict__ Q2, const bf16* __restrict__ K2,
    const bf16* __restrict__ V2, bf16* __restrict__ Y2)
{
    __shared__ bf16 lk[64 * 64];        // K tile [k][d], swizzled
    __shared__ bf16 lv[64 * 64];        // V tile [d][k], swizzled (from pre-transposed Vt)
    const int qt = blockIdx.x, h = blockIdx.y, z = blockIdx.z;
    const int b = z & 3, branch = z >> 2;
    const bf16* Q  = branch ? Q2 : Q1;
    const bf16* Km = branch ? K2 : K1;
    const bf16* Vt = branch ? V2 : V1;
    bf16*       Yo = branch ? Y2 : Y1;

    const int t = threadIdx.x;
    const int wave = t >> 6, lane = t & 63;
    const int l32 = lane & 31, hi = lane >> 5;
    const int sr = t >> 3, sb = t & 7;

    const int qrow0 = qt * 256 + wave * 64;    // this wave's 64 q rows

    // Q B-frags for the whole loop: [qb][ksd] -> Q[qrow0+qb*32+l32][ksd*16+hi*8 ..+7]
    short8 qf[2][4];
    #pragma unroll
    for (int qb = 0; qb < 2; ++qb) {
        const bf16* qptr = Q + (size_t)(b * Nn + qrow0 + qb * 32 + l32) * C1 + h * HD + hi * 8;
        #pragma unroll
        for (int ksd = 0; ksd < 4; ++ksd)
            qf[qb][ksd] = *(const short8*)(qptr + ksd * 16);
    }

    f32x16 o[2][2];                    // [qb][db] PV accumulators
    #pragma unroll
    for (int qb = 0; qb < 2; ++qb)
        #pragma unroll
        for (int db = 0; db < 2; ++db)
            o[qb][db] = (f32x16){0.f,0.f,0.f,0.f,0.f,0.f,0.f,0.f,0.f,0.f,0.f,0.f,0.f,0.f,0.f,0.f};
    float lsum[2] = {0.f, 0.f};

    const bf16* Kbase = Km + (size_t)b * Nn * C1 + h * HD;
    const bf16* Vbase = Vt + (size_t)(b * Hh + h) * 64 * Nn;

    // incremental staging pointers; register prefetch of first k-tile
    const bf16* kp0 = Kbase + (size_t)sr * C1 + sb * 8;
    const bf16* kp1 = kp0 + (size_t)32 * C1;
    const bf16* vp0 = Vbase + (size_t)sr * Nn + sb * 8;
    const bf16* vp1 = vp0 + (size_t)32 * Nn;
    short8 rk0 = *(const short8*)kp0;
    short8 rk1 = *(const short8*)kp1;
    short8 rv0 = *(const short8*)vp0;
    short8 rv1 = *(const short8*)vp1;

    const int NT = Nn / 64;
    for (int kt = 0; kt < NT; ++kt) {
        __syncthreads();                         // prior iter's readers done
        *(short8*)&lk[swz(sr, sb)]      = rk0;
        *(short8*)&lk[swz(sr + 32, sb)] = rk1;
        *(short8*)&lv[swz(sr, sb)]      = rv0;
        *(short8*)&lv[swz(sr + 32, sb)] = rv1;
        __syncthreads();
        if (kt + 1 < NT) {                       // prefetch next tile; overlaps compute
            kp0 += 64 * C1; kp1 += 64 * C1; vp0 += 64; vp1 += 64;
            rk0 = *(const short8*)kp0;
            rk1 = *(const short8*)kp1;
            rv0 = *(const short8*)vp0;
            rv1 = *(const short8*)vp1;
        }

        #pragma unroll
        for (int kb = 0; kb < 2; ++kb) {
            // K a-frags (row k = kb*32 + l32, d = ksd*16 + hi*8), reused by both qb
            short8 ka[4];
            #pragma unroll
            for (int ksd = 0; ksd < 4; ++ksd)
                ka[ksd] = *(const short8*)&lk[swz(kb * 32 + l32, ksd * 2 + hi)];

            short8 pa[2][2];   // [qb][ks] PV A-frags, built fully in-register
            #pragma unroll
            for (int qb = 0; qb < 2; ++qb) {
                f32x16 s = (f32x16){0.f,0.f,0.f,0.f,0.f,0.f,0.f,0.f,0.f,0.f,0.f,0.f,0.f,0.f,0.f,0.f};
                #pragma unroll
                for (int ksd = 0; ksd < 4; ++ksd)
                    s = __builtin_amdgcn_mfma_f32_32x32x16_bf16(ka[ksd], qf[qb][ksd], s, 0, 0, 0);
                // p[r] = P[q = l32][k = (r&3) + 8*(r>>2) + 4*hi] (within this kb)
                float p[16];
                #pragma unroll
                for (int r = 0; r < 16; ++r) p[r] = fexp2(s[r]);
                // lsum via packed-f32 adds: 7 pk_add + 2 scalar
                {
                    f32x2 t0 = pkadd((f32x2){p[0], p[1]},  (f32x2){p[2], p[3]});
                    f32x2 t1 = pkadd((f32x2){p[4], p[5]},  (f32x2){p[6], p[7]});
                    f32x2 t2 = pkadd((f32x2){p[8], p[9]},  (f32x2){p[10], p[11]});
                    f32x2 t3 = pkadd((f32x2){p[12], p[13]},(f32x2){p[14], p[15]});
                    t0 = pkadd(t0, t1);
                    t2 = pkadd(t2, t3);
                    t0 = pkadd(t0, t2);
                    lsum[qb] += t0.x + t0.y;
                }
                // ks=0 (k 0..15): dw0/dw2 from one swap, dw1/dw3 from the other
                unsigned d0 = cvtpk(p[0],  p[1]),  d2 = cvtpk(p[4],  p[5]);
                plswap(d0, d2);
                unsigned d1 = cvtpk(p[2],  p[3]),  d3 = cvtpk(p[6],  p[7]);
                plswap(d1, d3);
                pa[qb][0] = mk8(d0, d1, d2, d3);
                // ks=1 (k 16..31)
                unsigned e0 = cvtpk(p[8],  p[9]),  e2 = cvtpk(p[12], p[13]);
                plswap(e0, e2);
                unsigned e1 = cvtpk(p[10], p[11]), e3 = cvtpk(p[14], p[15]);
                plswap(e1, e3);
                pa[qb][1] = mk8(e0, e1, e2, e3);
            }

            // O += P V ; each V b-frag read once, reused by both qb
            #pragma unroll
            for (int ks = 0; ks < 2; ++ks) {
                #pragma unroll
                for (int db = 0; db < 2; ++db) {
                    short8 bv = *(const short8*)&lv[swz(db * 32 + l32, kb * 4 + ks * 2 + hi)];
                    o[0][db] = __builtin_amdgcn_mfma_f32_32x32x16_bf16(pa[0][ks], bv, o[0][db], 0, 0, 0);
                    o[1][db] = __builtin_amdgcn_mfma_f32_32x32x16_bf16(pa[1][ks], bv, o[1][db], 0, 0, 0);
                }
            }
        }
    }

    // epilogue: complete row sums across hi halves, redistribute to C/D rows, store
    #pragma unroll
    for (int qb = 0; qb < 2; ++qb) {
        float l = lsum[qb] + __shfl_xor(lsum[qb], 32, 64);  // row sum for q = qb*32 + l32
        float inv = 1.0f / l;
        #pragma unroll
        for (int r = 0; r < 16; ++r) {
            const int qr = (r & 3) + 8 * (r >> 2) + 4 * hi;  // C/D row for this reg
            float invr = __shfl(inv, qr, 64);
            size_t row = (size_t)(b * Nn + qrow0 + qb * 32 + qr);
            #pragma unroll
            for (int db = 0; db < 2; ++db)
                Yo[row * C1 + h * HD + db * 32 + l32] = __float2bfloat16(o[qb][db][r] * invr);
        }
    }
}

extern "C" void kernel_launch(void* const* d_in, const int* in_sizes, int n_in,
                              void* d_out, int out_size, void* d_ws, size_t ws_size,
                              hipStream_t stream)
{
    const float* x1   = (const float*)d_in[0];
    const float* x2   = (const float*)d_in[1];
    const float* q1w  = (const float*)d_in[2];
    const float* q2w  = (const float*)d_in[3];
    const float* kv1w = (const float*)d_in[4];
    const float* kv2w = (const float*)d_in[5];
    const float* p1w  = (const float*)d_in[6];
    const float* p1b  = (const float*)d_in[7];
    const float* p2w  = (const float*)d_in[8];
    const float* p2b  = (const float*)d_in[9];
    float* out = (float*)d_out;

    bf16* ws = (bf16*)d_ws;
    size_t o = 0;
    bf16* wq1  = ws + o; o += C1 * C1;
    bf16* wq2  = ws + o; o += C1 * C2;
    bf16* wkv1 = ws + o; o += 2 * C1 * C2;
    bf16* wkv2 = ws + o; o += 2 * C1 * C1;
    bf16* wp1  = ws + o; o += C1 * C1;
    bf16* wp2  = ws + o; o += C1 * C1;
    bf16* Q1   = ws + o; o += (size_t)Mm * C1;
    bf16* K1   = ws + o; o += (size_t)Mm * C1;
    bf16* V1t  = ws + o; o += (size_t)Mm * C1;      // [B,H,64,N]
    bf16* Q2   = ws + o; o += (size_t)Mm * C1;
    bf16* K2   = ws + o; o += (size_t)Mm * C1;
    bf16* V2t  = ws + o; o += (size_t)Mm * C1;
    bf16* Y1   = ws + o; o += (size_t)Mm * C1;
    bf16* Y2   = ws + o; o += (size_t)Mm * C1;
    (void)ws_size; (void)in_sizes; (void)n_in; (void)out_size;

    // convert WEIGHTS only (x1/x2 conversion fused into gemm_proj staging)
    CvtArgs ca;
    ca.s[0] = q1w;  ca.d[0] = wq1;  int n0 = C1 * C1;
    ca.s[1] = q2w;  ca.d[1] = wq2;  int n1 = C1 * C2;
    ca.s[2] = kv1w; ca.d[2] = wkv1; int n2 = 2 * C1 * C2;
    ca.s[3] = kv2w; ca.d[3] = wkv2; int n3 = 2 * C1 * C1;
    ca.s[4] = p1w;  ca.d[4] = wp1;  int n4 = C1 * C1;
    ca.s[5] = p2w;  ca.d[5] = wp2;  int n5 = C1 * C1;
    int ns[6] = {n0, n1, n2, n3, n4, n5};
    ca.off[0] = 0;
    for (int i = 0; i < 6; ++i) ca.off[i + 1] = ca.off[i] + ns[i];
    int total = ca.off[6];
    cvt_all<<<dim3((total / 4 + 255) / 256), 256, 0, stream>>>(ca);

    const float QS = 0.125f * 1.4426950408889634f;   // scale * log2(e), folded into Q

    // fused Q/KV projections (fp32 A inputs, conversion fused): grid 128 x 30
    // set0 (by 0-14):  x1, K=320: q1 -> Q1, kv2 -> K2,V2t
    // set1 (by 15-29): x2, K=256: q2 -> Q2, kv1 -> K1,V1t
    gemm_proj<<<dim3(Mm / 128, 30), 256, 0, stream>>>(
        x1, wq1, wkv2, x2, wq2, wkv1, QS,
        Q1, K2, V2t, Q2, K1, V1t);

    // attention, both branches in one launch; 256 q-rows per block (4 waves x 64 q)
    flash_kernel<<<dim3(Nn / 256, Hh, 2 * Bb), 256, 0, stream>>>(Q1, K1, V1t, Y1, Q2, K2, V2t, Y2);

    // fused output projections (bias + concat layout), z = branch
    gemm_out<<<dim3(Mm / 128, C1 / 64, 2), 256, 0, stream>>>(Y1, wp1, p1b, Y2, wp2, p2b, out);
}

// Round 10
// 336.336 us; speedup vs baseline: 1.0840x; 1.0229x over previous
//
#include <hip/hip_runtime.h>
#include <hip/hip_bf16.h>

#define Bb 4
#define Nn 4096
#define C1 320
#define C2 256
#define Hh 5
#define HD 64
#define Mm (Bb*Nn)   // 16384

using bf16 = __hip_bfloat16;
typedef __attribute__((ext_vector_type(8))) short  short8;   // 8 bf16 = one MFMA A/B frag
typedef __attribute__((ext_vector_type(4))) short  short4_;
typedef __attribute__((ext_vector_type(4))) float  f32x4;    // 16x16 MFMA C/D frag
typedef __attribute__((ext_vector_type(16))) float f32x16;   // 32x32 MFMA C/D frag

__device__ __forceinline__ short f2s(float f) {
    bf16 h = __float2bfloat16(f);
    short s;
    __builtin_memcpy(&s, &h, 2);
    return s;
}

__device__ __forceinline__ float fexp2(float x) {
#if __has_builtin(__builtin_amdgcn_exp2f)
    return __builtin_amdgcn_exp2f(x);
#else
    return exp2f(x);
#endif
}

// XOR-swizzled LDS tile addressing: 64-elem rows, 8 blocks of 8 bf16 (16B).
__device__ __forceinline__ int swz(int row, int bb) {
    return row * 64 + ((bb ^ (row & 7)) << 3);
}

// pack two f32 -> one dword of 2 bf16 (src0 -> low half), RNE (matches __float2bfloat16)
__device__ __forceinline__ unsigned cvtpk(float lo, float hi) {
    unsigned r;
    asm("v_cvt_pk_bf16_f32 %0, %1, %2" : "=v"(r) : "v"(lo), "v"(hi));
    return r;
}

// swap: a[lanes 32..63] <- b[lanes 0..31]; b[lanes 0..31] <- a[lanes 32..63]
__device__ __forceinline__ void plswap(unsigned &a, unsigned &b) {
#if __has_builtin(__builtin_amdgcn_permlane32_swap)
    auto r = __builtin_amdgcn_permlane32_swap(a, b, false, false);
    a = r[0]; b = r[1];
#else
    asm("v_permlane32_swap_b32 %0, %1" : "+v"(a), "+v"(b));
#endif
}

__device__ __forceinline__ short8 mk8(unsigned d0, unsigned d1, unsigned d2, unsigned d3) {
    union { unsigned u[4]; short8 s; } u;
    u.u[0] = d0; u.u[1] = d1; u.u[2] = d2; u.u[3] = d3;
    return u.s;
}

// convert 8 consecutive f32 (two float4) -> short8 of bf16
__device__ __forceinline__ short8 cvt8(float4 lo, float4 hi) {
    return mk8(cvtpk(lo.x, lo.y), cvtpk(lo.z, lo.w),
               cvtpk(hi.x, hi.y), cvtpk(hi.z, hi.w));
}

// ---------------- fp32 -> bf16 convert, WEIGHTS ONLY (x converts inside gemm_proj) ----
struct CvtArgs {
    const float* s[6];
    bf16* d[6];
    int off[7];   // cumulative offsets, off[6] = total
};

__global__ void cvt_all(CvtArgs a) {
    int i = (blockIdx.x * blockDim.x + threadIdx.x) * 4;
    if (i >= a.off[6]) return;
    int seg = 0;
    #pragma unroll
    for (int k = 1; k < 6; ++k) seg += (i >= a.off[k]);
    int j = i - a.off[seg];
    float4 v = *(const float4*)(a.s[seg] + j);
    short4_ o = { f2s(v.x), f2s(v.y), f2s(v.z), f2s(v.w) };
    *(short4_*)(a.d[seg] + j) = o;
}

// ---------------- fused projection GEMM: 128x64 tile, both inputs in one launch --------
// A inputs are the ORIGINAL fp32 x1/x2; conversion to bf16 is fused into A-staging.
// by in [0,30): g = by/15 selects input set (0: x1-set K=320, 1: x2-set K=256), yy = by%15.
// yy < 5 : Q-part:  Qo[row*320+col] = bf16(acc * qs)          (W = Wq,  Nout=320)
// yy >= 5: KV-part: col<320 -> Ko[row*320+col] = bf16(acc)    (W = Wkv, Nout=640)
//                   col>=320 -> Vo transposed [B,H,64,N]
__global__ __launch_bounds__(256) void gemm_proj(
    const float* __restrict__ A1, const bf16* __restrict__ Wq1, const bf16* __restrict__ Wkv1,
    const float* __restrict__ A2, const bf16* __restrict__ Wq2, const bf16* __restrict__ Wkv2,
    float qs,
    bf16* __restrict__ Qo1, bf16* __restrict__ Ko1, bf16* __restrict__ Vo1,
    bf16* __restrict__ Qo2, bf16* __restrict__ Ko2, bf16* __restrict__ Vo2)
{
    __shared__ bf16 la[128 * 64];
    __shared__ bf16 lw[64 * 64];
    const int m0 = blockIdx.x * 128;
    const int by = blockIdx.y;
    const int g = (by >= 15);
    const int yy = by - 15 * g;
    const int K = g ? C2 : C1;
    const float* A = g ? A2 : A1;
    const bool isq = yy < 5;
    const bf16* W = isq ? (g ? Wq2 : Wq1) : (g ? Wkv2 : Wkv1);
    bf16* Qo = g ? Qo2 : Qo1;
    bf16* Ko = g ? Ko2 : Ko1;
    bf16* Vo = g ? Vo2 : Vo1;
    const int n0 = (isq ? yy : yy - 5) * 64;
    const int t = threadIdx.x;
    const int wave = t >> 6, lane = t & 63, l16 = lane & 15, quad = lane >> 4;
    const int sr = t >> 3, sb = t & 7;      // sr 0..31, sb 0..7

    f32x4 acc[2][4];
    #pragma unroll
    for (int mf = 0; mf < 2; ++mf)
        #pragma unroll
        for (int nt = 0; nt < 4; ++nt) acc[mf][nt] = {0.f,0.f,0.f,0.f};

    const int nk = K >> 6;
    const float* ap = A + (size_t)(m0 + sr) * K + sb * 8;
    const bf16*  wp = W + (size_t)(n0 + sr) * K + sb * 8;
    float4 fa0 = *(const float4*)ap,                       fa0h = *(const float4*)(ap + 4);
    float4 fa1 = *(const float4*)(ap + (size_t)32 * K),    fa1h = *(const float4*)(ap + (size_t)32 * K + 4);
    float4 fa2 = *(const float4*)(ap + (size_t)64 * K),    fa2h = *(const float4*)(ap + (size_t)64 * K + 4);
    float4 fa3 = *(const float4*)(ap + (size_t)96 * K),    fa3h = *(const float4*)(ap + (size_t)96 * K + 4);
    short8 rw0 = *(const short8*)wp;
    short8 rw1 = *(const short8*)(wp + (size_t)32 * K);

    for (int kt = 0; kt < nk; ++kt) {
        __syncthreads();
        *(short8*)&la[swz(sr,      sb)] = cvt8(fa0, fa0h);
        *(short8*)&la[swz(sr + 32, sb)] = cvt8(fa1, fa1h);
        *(short8*)&la[swz(sr + 64, sb)] = cvt8(fa2, fa2h);
        *(short8*)&la[swz(sr + 96, sb)] = cvt8(fa3, fa3h);
        *(short8*)&lw[swz(sr,      sb)] = rw0;
        *(short8*)&lw[swz(sr + 32, sb)] = rw1;
        __syncthreads();
        if (kt + 1 < nk) {
            ap += 64; wp += 64;
            fa0 = *(const float4*)ap;                    fa0h = *(const float4*)(ap + 4);
            fa1 = *(const float4*)(ap + (size_t)32 * K); fa1h = *(const float4*)(ap + (size_t)32 * K + 4);
            fa2 = *(const float4*)(ap + (size_t)64 * K); fa2h = *(const float4*)(ap + (size_t)64 * K + 4);
            fa3 = *(const float4*)(ap + (size_t)96 * K); fa3h = *(const float4*)(ap + (size_t)96 * K + 4);
            rw0 = *(const short8*)wp;
            rw1 = *(const short8*)(wp + (size_t)32 * K);
        }
        const int arow = wave * 32 + l16;
        short8 a00 = *(const short8*)&la[swz(arow,      quad)];
        short8 a01 = *(const short8*)&la[swz(arow,      quad + 4)];
        short8 a10 = *(const short8*)&la[swz(arow + 16, quad)];
        short8 a11 = *(const short8*)&la[swz(arow + 16, quad + 4)];
        #pragma unroll
        for (int nt = 0; nt < 4; ++nt) {
            const int brow = nt * 16 + l16;
            short8 b0 = *(const short8*)&lw[swz(brow, quad)];
            short8 b1 = *(const short8*)&lw[swz(brow, quad + 4)];
            acc[0][nt] = __builtin_amdgcn_mfma_f32_16x16x32_bf16(a00, b0, acc[0][nt], 0, 0, 0);
            acc[0][nt] = __builtin_amdgcn_mfma_f32_16x16x32_bf16(a01, b1, acc[0][nt], 0, 0, 0);
            acc[1][nt] = __builtin_amdgcn_mfma_f32_16x16x32_bf16(a10, b0, acc[1][nt], 0, 0, 0);
            acc[1][nt] = __builtin_amdgcn_mfma_f32_16x16x32_bf16(a11, b1, acc[1][nt], 0, 0, 0);
        }
    }

    const bool isv = !isq && n0 >= C1;     // whole block is V-part or not
    #pragma unroll
    for (int mf = 0; mf < 2; ++mf) {
        const int mrow = m0 + wave * 32 + mf * 16 + quad * 4;
        if (isq) {
            #pragma unroll
            for (int nt = 0; nt < 4; ++nt) {
                int col = n0 + nt * 16 + l16;
                #pragma unroll
                for (int r = 0; r < 4; ++r)
                    Qo[(size_t)(mrow + r) * C1 + col] = __float2bfloat16(acc[mf][nt][r] * qs);
            }
        } else if (!isv) {
            #pragma unroll
            for (int nt = 0; nt < 4; ++nt) {
                int col = n0 + nt * 16 + l16;
                #pragma unroll
                for (int r = 0; r < 4; ++r)
                    Ko[(size_t)(mrow + r) * C1 + col] = __float2bfloat16(acc[mf][nt][r]);
            }
        } else {
            #pragma unroll
            for (int nt = 0; nt < 4; ++nt) {
                int col = n0 + nt * 16 + l16 - C1;
                int h = col >> 6, d = col & 63;
                #pragma unroll
                for (int r = 0; r < 4; ++r) {
                    int m = mrow + r;
                    int b = m >> 12, n = m & (Nn - 1);
                    Vo[((size_t)(b * Hh + h) * 64 + d) * Nn + n] = __float2bfloat16(acc[mf][nt][r]);
                }
            }
        }
    }
}

// ---------------- fused output projections: 128x64 tile, z = branch ----------------
__global__ __launch_bounds__(256) void gemm_out(
    const bf16* __restrict__ Y1, const bf16* __restrict__ Wp1, const float* __restrict__ B1,
    const bf16* __restrict__ Y2, const bf16* __restrict__ Wp2, const float* __restrict__ B2,
    float* __restrict__ Of)
{
    __shared__ bf16 la[128 * 64];
    __shared__ bf16 lw[64 * 64];
    const int zz = blockIdx.z;
    const bf16* A = zz ? Y2 : Y1;
    const bf16* W = zz ? Wp2 : Wp1;
    const float* bias = zz ? B2 : B1;
    const int ooff = zz ? C1 : 0;
    const int m0 = blockIdx.x * 128, n0 = blockIdx.y * 64;
    const int t = threadIdx.x;
    const int wave = t >> 6, lane = t & 63, l16 = lane & 15, quad = lane >> 4;
    const int sr = t >> 3, sb = t & 7;
    const int K = C1;

    f32x4 acc[2][4];
    #pragma unroll
    for (int mf = 0; mf < 2; ++mf)
        #pragma unroll
        for (int nt = 0; nt < 4; ++nt) acc[mf][nt] = {0.f,0.f,0.f,0.f};

    const int nk = K >> 6;
    const bf16* ap = A + (size_t)(m0 + sr) * K + sb * 8;
    const bf16* wp = W + (size_t)(n0 + sr) * K + sb * 8;
    short8 ra0 = *(const short8*)ap;
    short8 ra1 = *(const short8*)(ap + (size_t)32 * K);
    short8 ra2 = *(const short8*)(ap + (size_t)64 * K);
    short8 ra3 = *(const short8*)(ap + (size_t)96 * K);
    short8 rw0 = *(const short8*)wp;
    short8 rw1 = *(const short8*)(wp + (size_t)32 * K);

    for (int kt = 0; kt < nk; ++kt) {
        __syncthreads();
        *(short8*)&la[swz(sr,      sb)] = ra0;
        *(short8*)&la[swz(sr + 32, sb)] = ra1;
        *(short8*)&la[swz(sr + 64, sb)] = ra2;
        *(short8*)&la[swz(sr + 96, sb)] = ra3;
        *(short8*)&lw[swz(sr,      sb)] = rw0;
        *(short8*)&lw[swz(sr + 32, sb)] = rw1;
        __syncthreads();
        if (kt + 1 < nk) {
            ap += 64; wp += 64;
            ra0 = *(const short8*)ap;
            ra1 = *(const short8*)(ap + (size_t)32 * K);
            ra2 = *(const short8*)(ap + (size_t)64 * K);
            ra3 = *(const short8*)(ap + (size_t)96 * K);
            rw0 = *(const short8*)wp;
            rw1 = *(const short8*)(wp + (size_t)32 * K);
        }
        const int arow = wave * 32 + l16;
        short8 a00 = *(const short8*)&la[swz(arow,      quad)];
        short8 a01 = *(const short8*)&la[swz(arow,      quad + 4)];
        short8 a10 = *(const short8*)&la[swz(arow + 16, quad)];
        short8 a11 = *(const short8*)&la[swz(arow + 16, quad + 4)];
        #pragma unroll
        for (int nt = 0; nt < 4; ++nt) {
            const int brow = nt * 16 + l16;
            short8 b0 = *(const short8*)&lw[swz(brow, quad)];
            short8 b1 = *(const short8*)&lw[swz(brow, quad + 4)];
            acc[0][nt] = __builtin_amdgcn_mfma_f32_16x16x32_bf16(a00, b0, acc[0][nt], 0, 0, 0);
            acc[0][nt] = __builtin_amdgcn_mfma_f32_16x16x32_bf16(a01, b1, acc[0][nt], 0, 0, 0);
            acc[1][nt] = __builtin_amdgcn_mfma_f32_16x16x32_bf16(a10, b0, acc[1][nt], 0, 0, 0);
            acc[1][nt] = __builtin_amdgcn_mfma_f32_16x16x32_bf16(a11, b1, acc[1][nt], 0, 0, 0);
        }
    }

    #pragma unroll
    for (int mf = 0; mf < 2; ++mf) {
        const int mrow = m0 + wave * 32 + mf * 16 + quad * 4;
        #pragma unroll
        for (int nt = 0; nt < 4; ++nt) {
            int col = n0 + nt * 16 + l16;
            float bv = bias[col];
            #pragma unroll
            for (int r = 0; r < 4; ++r)
                Of[(size_t)(mrow + r) * 640 + ooff + col] = acc[mf][nt][r] + bv;
        }
    }
}

// ---------------- flash attention, both branches in one launch ----------------
// BYTE-EXACT R1 structure (best measured: 196.5 us, twice): 4 waves x 64 q
// (2 q-blocks of 32), KVBLK=64, 16KB swizzled LDS K/V tiles, 2 barriers/kt,
// register-prefetched staging with per-iteration recomputed addresses, scalar
// lsum adds. Swapped QK^T 32x32 MFMA (lane holds P-row slice: q = lane&31,
// k = (r&3)+8*(r>>2)+4*hi); in-register P->bf16 via cvt_pk + permlane32_swap;
// fixed m=0 softmax (Q pre-scaled by 0.125*log2e).
// NOTE: R8/R9 "sub-structural" variants (pk_add lsum tree, incremental ptrs)
// measured 210 us — inline-asm VALU trees damage scheduling (m240 lesson).
__global__ __launch_bounds__(256, 2) void flash_kernel(
    const bf16* __restrict__ Q1, const bf16* __restrict__ K1,
    const bf16* __restrict__ V1, bf16* __restrict__ Y1,
    const bf16* __restrict__ Q2, const bf16* __restrict__ K2,
    const bf16* __restrict__ V2, bf16* __restrict__ Y2)
{
    __shared__ bf16 lk[64 * 64];        // K tile [k][d], swizzled
    __shared__ bf16 lv[64 * 64];        // V tile [d][k], swizzled (from pre-transposed Vt)
    const int qt = blockIdx.x, h = blockIdx.y, z = blockIdx.z;
    const int b = z & 3, branch = z >> 2;
    const bf16* Q  = branch ? Q2 : Q1;
    const bf16* Km = branch ? K2 : K1;
    const bf16* Vt = branch ? V2 : V1;
    bf16*       Yo = branch ? Y2 : Y1;

    const int t = threadIdx.x;
    const int wave = t >> 6, lane = t & 63;
    const int l32 = lane & 31, hi = lane >> 5;
    const int sr = t >> 3, sb = t & 7;

    const int qrow0 = qt * 256 + wave * 64;    // this wave's 64 q rows

    // Q B-frags for the whole loop: [qb][ksd] -> Q[qrow0+qb*32+l32][ksd*16+hi*8 ..+7]
    short8 qf[2][4];
    #pragma unroll
    for (int qb = 0; qb < 2; ++qb) {
        const bf16* qptr = Q + (size_t)(b * Nn + qrow0 + qb * 32 + l32) * C1 + h * HD + hi * 8;
        #pragma unroll
        for (int ksd = 0; ksd < 4; ++ksd)
            qf[qb][ksd] = *(const short8*)(qptr + ksd * 16);
    }

    f32x16 o[2][2];                    // [qb][db] PV accumulators
    #pragma unroll
    for (int qb = 0; qb < 2; ++qb)
        #pragma unroll
        for (int db = 0; db < 2; ++db)
            o[qb][db] = (f32x16){0.f,0.f,0.f,0.f,0.f,0.f,0.f,0.f,0.f,0.f,0.f,0.f,0.f,0.f,0.f,0.f};
    float lsum[2] = {0.f, 0.f};

    const bf16* Kbase = Km + (size_t)b * Nn * C1 + h * HD;
    const bf16* Vbase = Vt + (size_t)(b * Hh + h) * 64 * Nn;

    // register prefetch of the first k-tile staging data
    short8 rk0 = *(const short8*)(Kbase + (size_t)sr * C1 + sb * 8);
    short8 rk1 = *(const short8*)(Kbase + (size_t)(sr + 32) * C1 + sb * 8);
    short8 rv0 = *(const short8*)(Vbase + (size_t)sr * Nn + sb * 8);
    short8 rv1 = *(const short8*)(Vbase + (size_t)(sr + 32) * Nn + sb * 8);

    const int NT = Nn / 64;
    for (int kt = 0; kt < NT; ++kt) {
        __syncthreads();                         // prior iter's readers done
        *(short8*)&lk[swz(sr, sb)]      = rk0;
        *(short8*)&lk[swz(sr + 32, sb)] = rk1;
        *(short8*)&lv[swz(sr, sb)]      = rv0;
        *(short8*)&lv[swz(sr + 32, sb)] = rv1;
        __syncthreads();
        if (kt + 1 < NT) {                       // prefetch next tile; overlaps compute
            const int kn = (kt + 1) * 64;
            rk0 = *(const short8*)(Kbase + (size_t)(kn + sr) * C1 + sb * 8);
            rk1 = *(const short8*)(Kbase + (size_t)(kn + sr + 32) * C1 + sb * 8);
            rv0 = *(const short8*)(Vbase + (size_t)sr * Nn + kn + sb * 8);
            rv1 = *(const short8*)(Vbase + (size_t)(sr + 32) * Nn + kn + sb * 8);
        }

        #pragma unroll
        for (int kb = 0; kb < 2; ++kb) {
            // K a-frags (row k = kb*32 + l32, d = ksd*16 + hi*8), reused by both qb
            short8 ka[4];
            #pragma unroll
            for (int ksd = 0; ksd < 4; ++ksd)
                ka[ksd] = *(const short8*)&lk[swz(kb * 32 + l32, ksd * 2 + hi)];

            short8 pa[2][2];   // [qb][ks] PV A-frags, built fully in-register
            #pragma unroll
            for (int qb = 0; qb < 2; ++qb) {
                f32x16 s = (f32x16){0.f,0.f,0.f,0.f,0.f,0.f,0.f,0.f,0.f,0.f,0.f,0.f,0.f,0.f,0.f,0.f};
                #pragma unroll
                for (int ksd = 0; ksd < 4; ++ksd)
                    s = __builtin_amdgcn_mfma_f32_32x32x16_bf16(ka[ksd], qf[qb][ksd], s, 0, 0, 0);
                // p[r] = P[q = l32][k = (r&3) + 8*(r>>2) + 4*hi] (within this kb)
                float p[16];
                #pragma unroll
                for (int r = 0; r < 16; ++r) p[r] = fexp2(s[r]);
                lsum[qb] += (((p[0]+p[1])+(p[2]+p[3])) + ((p[4]+p[5])+(p[6]+p[7])))
                          + (((p[8]+p[9])+(p[10]+p[11])) + ((p[12]+p[13])+(p[14]+p[15])));
                // ks=0 (k 0..15): dw0/dw2 from one swap, dw1/dw3 from the other
                unsigned d0 = cvtpk(p[0],  p[1]),  d2 = cvtpk(p[4],  p[5]);
                plswap(d0, d2);
                unsigned d1 = cvtpk(p[2],  p[3]),  d3 = cvtpk(p[6],  p[7]);
                plswap(d1, d3);
                pa[qb][0] = mk8(d0, d1, d2, d3);
                // ks=1 (k 16..31)
                unsigned e0 = cvtpk(p[8],  p[9]),  e2 = cvtpk(p[12], p[13]);
                plswap(e0, e2);
                unsigned e1 = cvtpk(p[10], p[11]), e3 = cvtpk(p[14], p[15]);
                plswap(e1, e3);
                pa[qb][1] = mk8(e0, e1, e2, e3);
            }

            // O += P V ; each V b-frag read once, reused by both qb
            #pragma unroll
            for (int ks = 0; ks < 2; ++ks) {
                #pragma unroll
                for (int db = 0; db < 2; ++db) {
                    short8 bv = *(const short8*)&lv[swz(db * 32 + l32, kb * 4 + ks * 2 + hi)];
                    o[0][db] = __builtin_amdgcn_mfma_f32_32x32x16_bf16(pa[0][ks], bv, o[0][db], 0, 0, 0);
                    o[1][db] = __builtin_amdgcn_mfma_f32_32x32x16_bf16(pa[1][ks], bv, o[1][db], 0, 0, 0);
                }
            }
        }
    }

    // epilogue: complete row sums across hi halves, redistribute to C/D rows, store
    #pragma unroll
    for (int qb = 0; qb < 2; ++qb) {
        float l = lsum[qb] + __shfl_xor(lsum[qb], 32, 64);  // row sum for q = qb*32 + l32
        float inv = 1.0f / l;
        #pragma unroll
        for (int r = 0; r < 16; ++r) {
            const int qr = (r & 3) + 8 * (r >> 2) + 4 * hi;  // C/D row for this reg
            float invr = __shfl(inv, qr, 64);
            size_t row = (size_t)(b * Nn + qrow0 + qb * 32 + qr);
            #pragma unroll
            for (int db = 0; db < 2; ++db)
                Yo[row * C1 + h * HD + db * 32 + l32] = __float2bfloat16(o[qb][db][r] * invr);
        }
    }
}

extern "C" void kernel_launch(void* const* d_in, const int* in_sizes, int n_in,
                              void* d_out, int out_size, void* d_ws, size_t ws_size,
                              hipStream_t stream)
{
    const float* x1   = (const float*)d_in[0];
    const float* x2   = (const float*)d_in[1];
    const float* q1w  = (const float*)d_in[2];
    const float* q2w  = (const float*)d_in[3];
    const float* kv1w = (const float*)d_in[4];
    const float* kv2w = (const float*)d_in[5];
    const float* p1w  = (const float*)d_in[6];
    const float* p1b  = (const float*)d_in[7];
    const float* p2w  = (const float*)d_in[8];
    const float* p2b  = (const float*)d_in[9];
    float* out = (float*)d_out;

    bf16* ws = (bf16*)d_ws;
    size_t o = 0;
    bf16* wq1  = ws + o; o += C1 * C1;
    bf16* wq2  = ws + o; o += C1 * C2;
    bf16* wkv1 = ws + o; o += 2 * C1 * C2;
    bf16* wkv2 = ws + o; o += 2 * C1 * C1;
    bf16* wp1  = ws + o; o += C1 * C1;
    bf16* wp2  = ws + o; o += C1 * C1;
    bf16* Q1   = ws + o; o += (size_t)Mm * C1;
    bf16* K1   = ws + o; o += (size_t)Mm * C1;
    bf16* V1t  = ws + o; o += (size_t)Mm * C1;      // [B,H,64,N]
    bf16* Q2   = ws + o; o += (size_t)Mm * C1;
    bf16* K2   = ws + o; o += (size_t)Mm * C1;
    bf16* V2t  = ws + o; o += (size_t)Mm * C1;
    bf16* Y1   = ws + o; o += (size_t)Mm * C1;
    bf16* Y2   = ws + o; o += (size_t)Mm * C1;
    (void)ws_size; (void)in_sizes; (void)n_in; (void)out_size;

    // convert WEIGHTS only (x1/x2 conversion fused into gemm_proj staging)
    CvtArgs ca;
    ca.s[0] = q1w;  ca.d[0] = wq1;  int n0 = C1 * C1;
    ca.s[1] = q2w;  ca.d[1] = wq2;  int n1 = C1 * C2;
    ca.s[2] = kv1w; ca.d[2] = wkv1; int n2 = 2 * C1 * C2;
    ca.s[3] = kv2w; ca.d[3] = wkv2; int n3 = 2 * C1 * C1;
    ca.s[4] = p1w;  ca.d[4] = wp1;  int n4 = C1 * C1;
    ca.s[5] = p2w;  ca.d[5] = wp2;  int n5 = C1 * C1;
    int ns[6] = {n0, n1, n2, n3, n4, n5};
    ca.off[0] = 0;
    for (int i = 0; i < 6; ++i) ca.off[i + 1] = ca.off[i] + ns[i];
    int total = ca.off[6];
    cvt_all<<<dim3((total / 4 + 255) / 256), 256, 0, stream>>>(ca);

    const float QS = 0.125f * 1.4426950408889634f;   // scale * log2(e), folded into Q

    // fused Q/KV projections (fp32 A inputs, conversion fused): grid 128 x 30
    // set0 (by 0-14):  x1, K=320: q1 -> Q1, kv2 -> K2,V2t
    // set1 (by 15-29): x2, K=256: q2 -> Q2, kv1 -> K1,V1t
    gemm_proj<<<dim3(Mm / 128, 30), 256, 0, stream>>>(
        x1, wq1, wkv2, x2, wq2, wkv1, QS,
        Q1, K2, V2t, Q2, K1, V1t);

    // attention, both branches in one launch; 256 q-rows per block (4 waves x 64 q)
    flash_kernel<<<dim3(Nn / 256, Hh, 2 * Bb), 256, 0, stream>>>(Q1, K1, V1t, Y1, Q2, K2, V2t, Y2);

    // fused output projections (bias + concat layout), z = branch
    gemm_out<<<dim3(Mm / 128, C1 / 64, 2), 256, 0, stream>>>(Y1, wp1, p1b, Y2, wp2, p2b, out);
}